// Round 2
// baseline (391.121 us; speedup 1.0000x reference)
//
#include <hip/hip_runtime.h>

typedef __bf16 bf16_t;
typedef __bf16 bf16x8 __attribute__((ext_vector_type(8)));
typedef __bf16 bf16x4v __attribute__((ext_vector_type(4)));
typedef float f32x4 __attribute__((ext_vector_type(4)));

#define LN_EPS 1e-5f

// A&S 7.1.26 erf (|err|<=1.5e-7), branch-free
__device__ __forceinline__ float gelu_f(float x) {
  const float xs = x * 0.70710678118654752f;
  const float ax = fabsf(xs);
  const float t = __builtin_amdgcn_rcpf(fmaf(0.3275911f, ax, 1.0f));
  float y = fmaf(t, 1.061405429f, -1.453152027f);
  y = fmaf(t, y, 1.421413741f);
  y = fmaf(t, y, -0.284496736f);
  y = fmaf(t, y, 0.254829592f);
  y *= t;
  const float e = __expf(-ax * ax);
  const float er = fmaf(-y, e, 1.0f);          // erf(|xs|)
  return 0.5f * x * (1.0f + copysignf(er, xs));
}

__device__ __forceinline__ void async16(const bf16_t* g, bf16_t* l) {
  __builtin_amdgcn_global_load_lds(
      (const __attribute__((address_space(1))) void*)g,
      (__attribute__((address_space(3))) void*)l, 16, 0, 0);
}

// ---------------------------------------------------------------------------
// prep: X,S -> bf16 ; weights -> transposed (N-major) bf16
// ---------------------------------------------------------------------------
__global__ __launch_bounds__(256)
void prep_kernel(const float* __restrict__ X, const float* __restrict__ S,
                 const float* __restrict__ Wg, const float* __restrict__ Wk,
                 const float* __restrict__ Wm1, const float* __restrict__ Wgt1,
                 const float* __restrict__ Wm2, const float* __restrict__ Wqkv,
                 const float* __restrict__ Wo, const float* __restrict__ Wu1,
                 const float* __restrict__ Wu2,
                 bf16_t* __restrict__ Xb, bf16_t* __restrict__ Sb,
                 bf16_t* __restrict__ W1t, bf16_t* __restrict__ W2t,
                 bf16_t* __restrict__ Wqkvt, bf16_t* __restrict__ Wot,
                 bf16_t* __restrict__ Wu1t, bf16_t* __restrict__ Wu2t)
{
  const int bid = blockIdx.x;
  const int t = threadIdx.x;
  if (bid < 8192) {                       // X: 2,097,152 float4
    const int i = bid * 256 + t;
    const float4 v = ((const float4*)X)[i];
    bf16x4v o; o[0]=(bf16_t)v.x; o[1]=(bf16_t)v.y; o[2]=(bf16_t)v.z; o[3]=(bf16_t)v.w;
    ((bf16x4v*)Xb)[i] = o;
  } else if (bid < 9216) {                // S
    const int i = (bid - 8192) * 256 + t;
    const float4 v = ((const float4*)S)[i];
    bf16x4v o; o[0]=(bf16_t)v.x; o[1]=(bf16_t)v.y; o[2]=(bf16_t)v.z; o[3]=(bf16_t)v.w;
    ((bf16x4v*)Sb)[i] = o;
  } else if (bid < 10112) {               // W1t: 896 rows x 256
    const int n = bid - 9216;
    const int k = t;
    float v;
    if (n < 512)      v = Wm1[k * 512 + n];
    else if (n < 768) v = Wgt1[k * 256 + (n - 512)];
    else if (n < 832) v = Wg[k * 64 + (n - 768)];
    else if (n < 840) v = Wk[k * 8 + (n - 832)];
    else              v = 0.f;
    W1t[n * 256 + k] = (bf16_t)v;
  } else if (bid < 10368) {               // W2t: 256 rows x 512
    const int n = bid - 10112;
    for (int k = t; k < 512; k += 256) W2t[n * 512 + k] = (bf16_t)Wm2[k * 256 + n];
  } else if (bid < 11136) {               // Wqkvt: 768 x 256
    const int n = bid - 10368;
    Wqkvt[n * 256 + t] = (bf16_t)Wqkv[t * 768 + n];
  } else if (bid < 11392) {               // Wot: 256 x 256
    const int n = bid - 11136;
    Wot[n * 256 + t] = (bf16_t)Wo[t * 256 + n];
  } else if (bid < 11904) {               // Wu1t: 512 x 512
    const int n = bid - 11392;
    for (int k = t; k < 512; k += 256) Wu1t[n * 512 + k] = (bf16_t)Wu1[k * 512 + n];
  } else {                                // Wu2t: 256 x 512
    const int n = bid - 11904;
    for (int k = t; k < 512; k += 256) Wu2t[n * 512 + k] = (bf16_t)Wu2[k * 256 + n];
  }
}

// ---------------------------------------------------------------------------
// generic bf16 MFMA GEMM: C[M x N] = A[M x K] * Bt[N x K]^T, tile BMx128
// MFMA operands SWAPPED (Bt-frag as "A", A-frag as "B") so each lane's 4
// accumulator regs are 4 CONSECUTIVE COLUMNS of one row -> vectorized stores.
// EPI: 1=gelu(+bm1/bgt1)->bf16 (G1, raw logits for col>=768)
//      2=(c+bias)*gate -> atomicAdd incoming (G2 scatter)
//      3=+bias->bf16   4=+bias->f32   5=gelu(+bias)->bf16   6=+bias+resid->f32
// ---------------------------------------------------------------------------
template<int MT, int EPI>
__global__ __launch_bounds__(256)
void gemm_kernel(const bf16_t* __restrict__ A, int lda,
                 const bf16_t* __restrict__ Bt, int K,
                 const float* __restrict__ bias, const float* __restrict__ bias2,
                 void* __restrict__ outp, int ldc,
                 const float* __restrict__ gate, const int* __restrict__ slotidx,
                 float* __restrict__ incoming, const float* __restrict__ resid)
{
  constexpr int BM = MT * 32;
  constexpr int IA = (BM * 4) / 256;
  const int m0 = blockIdx.x * BM;
  const int n0 = blockIdx.y * 128;
  const int t = threadIdx.x;
  const int w = t >> 6;
  const int lane = t & 63;
  const int wr = w >> 1, wc = w & 1;
  const int quad = lane >> 4, l15 = lane & 15;

  __shared__ bf16_t lA[BM * 32];
  __shared__ bf16_t lB[128 * 32];

  f32x4 acc[MT][4];
#pragma unroll
  for (int mt = 0; mt < MT; ++mt)
#pragma unroll
    for (int nt = 0; nt < 4; ++nt)
      acc[mt][nt] = (f32x4){0.f, 0.f, 0.f, 0.f};

  for (int k0 = 0; k0 < K; k0 += 32) {
#pragma unroll
    for (int i = 0; i < IA; ++i) {
      const int c = i * 256 + t;
      async16(A + (size_t)(m0 + (c >> 2)) * lda + k0 + (c & 3) * 8,
              lA + (size_t)(i * 256 + (t & 192)) * 8);
    }
#pragma unroll
    for (int i = 0; i < 2; ++i) {
      const int c = i * 256 + t;
      async16(Bt + (size_t)(n0 + (c >> 2)) * K + k0 + (c & 3) * 8,
              lB + (size_t)(i * 256 + (t & 192)) * 8);
    }
    __syncthreads();
    bf16x8 af[MT], bfr[4];
    const int ko = quad * 8;
#pragma unroll
    for (int mt = 0; mt < MT; ++mt)
      af[mt] = *(const bf16x8*)&lA[(wr * MT * 16 + mt * 16 + l15) * 32 + ko];
#pragma unroll
    for (int nt = 0; nt < 4; ++nt)
      bfr[nt] = *(const bf16x8*)&lB[(wc * 64 + nt * 16 + l15) * 32 + ko];
#pragma unroll
    for (int mt = 0; mt < MT; ++mt)
#pragma unroll
      for (int nt = 0; nt < 4; ++nt)
        acc[mt][nt] = __builtin_amdgcn_mfma_f32_16x16x32_bf16(bfr[nt], af[mt], acc[mt][nt], 0, 0, 0);
    __syncthreads();
  }

  // epilogue: lane holds row = ...+l15, cols = colb..colb+3 (consecutive)
#pragma unroll
  for (int mt = 0; mt < MT; ++mt) {
    const int row = m0 + wr * MT * 16 + mt * 16 + l15;
    float gt = 0.f; float* dst = nullptr;
    if constexpr (EPI == 2) {
      gt = gate[row];
      dst = incoming + (size_t)(((row >> 12) << 9) + slotidx[row]) * 256;
    }
#pragma unroll
    for (int nt = 0; nt < 4; ++nt) {
      const int colb = n0 + wc * 64 + nt * 16 + quad * 4;
      float v0 = acc[mt][nt][0], v1 = acc[mt][nt][1];
      float v2 = acc[mt][nt][2], v3 = acc[mt][nt][3];
      if constexpr (EPI == 1) {
        if (colb < 768) {
          const float* bp = (colb < 512) ? (bias + colb) : (bias2 + (colb - 512));
          const float4 bb = *(const float4*)bp;
          v0 = gelu_f(v0 + bb.x); v1 = gelu_f(v1 + bb.y);
          v2 = gelu_f(v2 + bb.z); v3 = gelu_f(v3 + bb.w);
        }
        bf16x4v o; o[0]=(bf16_t)v0; o[1]=(bf16_t)v1; o[2]=(bf16_t)v2; o[3]=(bf16_t)v3;
        *(bf16x4v*)&((bf16_t*)outp)[(size_t)row * ldc + colb] = o;
      } else if constexpr (EPI == 2) {
        const float4 bb = *(const float4*)&bias[colb];
        atomicAdd(dst + colb + 0, (v0 + bb.x) * gt);
        atomicAdd(dst + colb + 1, (v1 + bb.y) * gt);
        atomicAdd(dst + colb + 2, (v2 + bb.z) * gt);
        atomicAdd(dst + colb + 3, (v3 + bb.w) * gt);
      } else if constexpr (EPI == 3) {
        const float4 bb = *(const float4*)&bias[colb];
        bf16x4v o; o[0]=(bf16_t)(v0+bb.x); o[1]=(bf16_t)(v1+bb.y);
        o[2]=(bf16_t)(v2+bb.z); o[3]=(bf16_t)(v3+bb.w);
        *(bf16x4v*)&((bf16_t*)outp)[(size_t)row * ldc + colb] = o;
      } else if constexpr (EPI == 4) {
        const float4 bb = *(const float4*)&bias[colb];
        float4 o = make_float4(v0+bb.x, v1+bb.y, v2+bb.z, v3+bb.w);
        *(float4*)&((float*)outp)[(size_t)row * ldc + colb] = o;
      } else if constexpr (EPI == 5) {
        const float4 bb = *(const float4*)&bias[colb];
        bf16x4v o; o[0]=(bf16_t)gelu_f(v0+bb.x); o[1]=(bf16_t)gelu_f(v1+bb.y);
        o[2]=(bf16_t)gelu_f(v2+bb.z); o[3]=(bf16_t)gelu_f(v3+bb.w);
        *(bf16x4v*)&((bf16_t*)outp)[(size_t)row * ldc + colb] = o;
      } else {
        const float4 bb = *(const float4*)&bias[colb];
        const float4 rr = *(const float4*)&resid[(size_t)row * ldc + colb];
        float4 o = make_float4(v0+bb.x+rr.x, v1+bb.y+rr.y, v2+bb.z+rr.z, v3+bb.w+rr.w);
        *(float4*)&((float*)outp)[(size_t)row * ldc + colb] = o;
      }
    }
  }
}

// ---------------------------------------------------------------------------
// route: gate = sigmoid(g1.Wgt2 + bgt2); idx = argmax(g)*8 + argmax(k)
// ---------------------------------------------------------------------------
__global__ __launch_bounds__(256)
void route_kernel(const bf16_t* __restrict__ h1g1, const float* __restrict__ Wgt2,
                  const float* __restrict__ bgt2, int* __restrict__ idxb,
                  float* __restrict__ gateb)
{
  const int w = threadIdx.x >> 6, lane = threadIdx.x & 63;
  const int m = blockIdx.x * 4 + w;
  const bf16_t* rowp = h1g1 + (size_t)m * 896;

  bf16x4v g4 = *(const bf16x4v*)&rowp[512 + lane * 4];
  float s = 0.f;
#pragma unroll
  for (int j = 0; j < 4; ++j) s += (float)g4[j] * Wgt2[lane * 4 + j];
#pragma unroll
  for (int off = 32; off; off >>= 1) s += __shfl_xor(s, off, 64);
  const float gate = 1.0f / (1.0f + __expf(-(s + bgt2[0])));

  float vg = (float)rowp[768 + lane];
  int ig = lane;
#pragma unroll
  for (int off = 32; off; off >>= 1) {
    const float ov = __shfl_xor(vg, off, 64);
    const int oi = __shfl_xor(ig, off, 64);
    if (ov > vg || (ov == vg && oi < ig)) { vg = ov; ig = oi; }
  }
  float vk = (lane < 8) ? (float)rowp[832 + lane] : -1e30f;
  int ik = lane;
#pragma unroll
  for (int off = 32; off; off >>= 1) {
    const float ov = __shfl_xor(vk, off, 64);
    const int oi = __shfl_xor(ik, off, 64);
    if (ov > vk || (ov == vk && oi < ik)) { vk = ov; ik = oi; }
  }
  if (lane == 0) { idxb[m] = ig * 8 + ik; gateb[m] = gate; }
}

// ---------------------------------------------------------------------------
// fused slot attention: block = (b, h, 32-query chunk)
// ---------------------------------------------------------------------------
__global__ __launch_bounds__(256)
void attn_kernel(const bf16_t* __restrict__ qkv, bf16_t* __restrict__ obuf)
{
  const int bid = blockIdx.x;
  const int qc = bid & 15;
  const int h = (bid >> 4) & 7;
  const int b = bid >> 7;
  const int t = threadIdx.x;
  const int w = t >> 6, lane = t & 63;
  const int quad = lane >> 4, l15 = lane & 15;

  __shared__ bf16_t sP[32 * 520];
  __shared__ bf16_t sVt[32 * 264];
  __shared__ float sL[32];

  bf16x8 qf[2];
#pragma unroll
  for (int mt = 0; mt < 2; ++mt) {
    const int row = b * 512 + qc * 32 + mt * 16 + l15;
    qf[mt] = *(const bf16x8*)&qkv[(size_t)row * 768 + h * 32 + quad * 8];
  }
  const float scale = 0.17677669529663687f;  // 1/sqrt(32)
  for (int kt = w; kt < 32; kt += 4) {
    const int key = b * 512 + kt * 16 + l15;
    const bf16x8 kf = *(const bf16x8*)&qkv[(size_t)key * 768 + 256 + h * 32 + quad * 8];
#pragma unroll
    for (int mt = 0; mt < 2; ++mt) {
      f32x4 c = (f32x4){0.f, 0.f, 0.f, 0.f};
      c = __builtin_amdgcn_mfma_f32_16x16x32_bf16(qf[mt], kf, c, 0, 0, 0);
#pragma unroll
      for (int r = 0; r < 4; ++r)
        sP[(mt * 16 + quad * 4 + r) * 520 + kt * 16 + l15] = (bf16_t)(c[r] * scale);
    }
  }
  __syncthreads();

#pragma unroll
  for (int ri = 0; ri < 8; ++ri) {
    const int row = w * 8 + ri;
    const bf16x8 sv = *(const bf16x8*)&sP[row * 520 + lane * 8];
    float sval[8];
    float mx = -1e30f;
#pragma unroll
    for (int j = 0; j < 8; ++j) { sval[j] = (float)sv[j]; mx = fmaxf(mx, sval[j]); }
#pragma unroll
    for (int off = 32; off; off >>= 1) mx = fmaxf(mx, __shfl_xor(mx, off, 64));
    float sum = 0.f;
    bf16x8 pv;
#pragma unroll
    for (int j = 0; j < 8; ++j) { const float e = __expf(sval[j] - mx); sum += e; pv[j] = (bf16_t)e; }
#pragma unroll
    for (int off = 32; off; off >>= 1) sum += __shfl_xor(sum, off, 64);
    *(bf16x8*)&sP[row * 520 + lane * 8] = pv;
    if (lane == 0) sL[row] = sum;
  }
  __syncthreads();

  const int omt = w >> 1, ont = w & 1;
  f32x4 oacc = (f32x4){0.f, 0.f, 0.f, 0.f};
  for (int half = 0; half < 2; ++half) {
    if (half) __syncthreads();
#pragma unroll
    for (int i = 0; i < 32; ++i) {
      const int el = i * 256 + t;
      const int dh = el & 31, key = el >> 5;
      sVt[dh * 264 + key] = qkv[(size_t)(b * 512 + half * 256 + key) * 768 + 512 + h * 32 + dh];
    }
    __syncthreads();
#pragma unroll
    for (int kt = 0; kt < 8; ++kt) {
      const bf16x8 af = *(const bf16x8*)&sP[(omt * 16 + l15) * 520 + half * 256 + kt * 32 + quad * 8];
      const bf16x8 vf = *(const bf16x8*)&sVt[(ont * 16 + l15) * 264 + kt * 32 + quad * 8];
      oacc = __builtin_amdgcn_mfma_f32_16x16x32_bf16(af, vf, oacc, 0, 0, 0);
    }
  }
#pragma unroll
  for (int r = 0; r < 4; ++r) {
    const int row = omt * 16 + quad * 4 + r;
    const float val = oacc[r] / sL[row];
    obuf[(size_t)(b * 512 + qc * 32 + row) * 256 + h * 32 + ont * 16 + l15] = (bf16_t)val;
  }
}

// ---------------------------------------------------------------------------
__global__ __launch_bounds__(256)
void ln1_kernel(const float* __restrict__ S, const float* __restrict__ o2,
                const float* __restrict__ incom, const float* __restrict__ g,
                const float* __restrict__ bb, float* __restrict__ S1f,
                bf16_t* __restrict__ A4)
{
  const int w = threadIdx.x >> 6, lane = threadIdx.x & 63;
  const int row = blockIdx.x * 4 + w;
  const size_t base = (size_t)row * 256 + lane * 4;
  const float4 xs = *(const float4*)&S[base];
  const float4 xo = *(const float4*)&o2[base];
  float x[4] = {xs.x + xo.x, xs.y + xo.y, xs.z + xo.z, xs.w + xo.w};
  float sum = x[0] + x[1] + x[2] + x[3];
  float sq = x[0]*x[0] + x[1]*x[1] + x[2]*x[2] + x[3]*x[3];
#pragma unroll
  for (int off = 32; off; off >>= 1) { sum += __shfl_xor(sum, off, 64); sq += __shfl_xor(sq, off, 64); }
  const float mean = sum * 0.00390625f;
  const float var = sq * 0.00390625f - mean * mean;
  const float rstd = rsqrtf(var + LN_EPS);
  const float4 gg = *(const float4*)&g[lane * 4];
  const float4 bv = *(const float4*)&bb[lane * 4];
  float y[4];
  y[0] = (x[0]-mean)*rstd*gg.x + bv.x;
  y[1] = (x[1]-mean)*rstd*gg.y + bv.y;
  y[2] = (x[2]-mean)*rstd*gg.z + bv.z;
  y[3] = (x[3]-mean)*rstd*gg.w + bv.w;
  *(float4*)&S1f[base] = make_float4(y[0], y[1], y[2], y[3]);
  bf16x4v yb; yb[0]=(bf16_t)y[0]; yb[1]=(bf16_t)y[1]; yb[2]=(bf16_t)y[2]; yb[3]=(bf16_t)y[3];
  *(bf16x4v*)&A4[(size_t)row * 512 + lane * 4] = yb;
  const float4 ic = *(const float4*)&incom[base];
  bf16x4v ib; ib[0]=(bf16_t)ic.x; ib[1]=(bf16_t)ic.y; ib[2]=(bf16_t)ic.z; ib[3]=(bf16_t)ic.w;
  *(bf16x4v*)&A4[(size_t)row * 512 + 256 + lane * 4] = ib;
}

__global__ __launch_bounds__(256)
void ln2_kernel(const float* __restrict__ S2, const float* __restrict__ g,
                const float* __restrict__ bb, float* __restrict__ out)
{
  const int w = threadIdx.x >> 6, lane = threadIdx.x & 63;
  const int row = blockIdx.x * 4 + w;
  const size_t base = (size_t)row * 256 + lane * 4;
  const float4 xv = *(const float4*)&S2[base];
  float x[4] = {xv.x, xv.y, xv.z, xv.w};
  float sum = x[0] + x[1] + x[2] + x[3];
  float sq = x[0]*x[0] + x[1]*x[1] + x[2]*x[2] + x[3]*x[3];
#pragma unroll
  for (int off = 32; off; off >>= 1) { sum += __shfl_xor(sum, off, 64); sq += __shfl_xor(sq, off, 64); }
  const float mean = sum * 0.00390625f;
  const float var = sq * 0.00390625f - mean * mean;
  const float rstd = rsqrtf(var + LN_EPS);
  const float4 gg = *(const float4*)&g[lane * 4];
  const float4 bv = *(const float4*)&bb[lane * 4];
  float4 o;
  o.x = (x[0]-mean)*rstd*gg.x + bv.x;
  o.y = (x[1]-mean)*rstd*gg.y + bv.y;
  o.z = (x[2]-mean)*rstd*gg.z + bv.z;
  o.w = (x[3]-mean)*rstd*gg.w + bv.w;
  *(float4*)&out[base] = o;
}

// ---------------------------------------------------------------------------
extern "C" void kernel_launch(void* const* d_in, const int* in_sizes, int n_in,
                              void* d_out, int out_size, void* d_ws, size_t ws_size,
                              hipStream_t stream)
{
  (void)in_sizes; (void)n_in; (void)out_size; (void)ws_size;
  const float* X    = (const float*)d_in[0];
  const float* S    = (const float*)d_in[1];
  const float* Wg   = (const float*)d_in[2];
  const float* Wk   = (const float*)d_in[3];
  const float* Wm1  = (const float*)d_in[4];
  const float* bm1  = (const float*)d_in[5];
  const float* Wm2  = (const float*)d_in[6];
  const float* bm2  = (const float*)d_in[7];
  const float* Wgt1 = (const float*)d_in[8];
  const float* bgt1 = (const float*)d_in[9];
  const float* Wgt2 = (const float*)d_in[10];
  const float* bgt2 = (const float*)d_in[11];
  const float* Wqkv = (const float*)d_in[12];
  const float* bqkv = (const float*)d_in[13];
  const float* Wo   = (const float*)d_in[14];
  const float* bo   = (const float*)d_in[15];
  const float* alng = (const float*)d_in[16];
  const float* alnb = (const float*)d_in[17];
  const float* Wu1  = (const float*)d_in[18];
  const float* bu1  = (const float*)d_in[19];
  const float* Wu2  = (const float*)d_in[20];
  const float* bu2  = (const float*)d_in[21];
  const float* lng  = (const float*)d_in[22];
  const float* lnb  = (const float*)d_in[23];

  char* p = (char*)d_ws;
  auto carve = [&](size_t bytes) { char* r = p; p += bytes; return r; };
  bf16_t* Xb    = (bf16_t*)carve(16777216);   // 32768 x 256
  bf16_t* Sb    = (bf16_t*)carve(2097152);    // 4096 x 256
  bf16_t* W1t   = (bf16_t*)carve(458752);     // 896 x 256
  bf16_t* W2t   = (bf16_t*)carve(262144);     // 256 x 512
  bf16_t* Wqkvt = (bf16_t*)carve(393216);     // 768 x 256
  bf16_t* Wot   = (bf16_t*)carve(131072);     // 256 x 256
  bf16_t* Wu1t  = (bf16_t*)carve(524288);     // 512 x 512
  bf16_t* Wu2t  = (bf16_t*)carve(262144);     // 256 x 512
  bf16_t* h1g1  = (bf16_t*)carve(58720256);   // 32768 x 896
  int*    idxb  = (int*)carve(131072);
  float*  gateb = (float*)carve(131072);
  float*  incom = (float*)carve(4194304);     // 4096 x 256 f32
  bf16_t* qkvb  = (bf16_t*)carve(6291456);    // 4096 x 768
  bf16_t* obuf  = (bf16_t*)carve(2097152);    // 4096 x 256
  float*  o2    = (float*)carve(4194304);
  float*  S1f   = (float*)carve(4194304);
  bf16_t* A4    = (bf16_t*)carve(4194304);    // 4096 x 512
  bf16_t* U     = (bf16_t*)carve(4194304);    // 4096 x 512
  float*  S2    = (float*)carve(4194304);

  prep_kernel<<<12160, 256, 0, stream>>>(X, S, Wg, Wk, Wm1, Wgt1, Wm2, Wqkv, Wo, Wu1, Wu2,
                                         Xb, Sb, W1t, W2t, Wqkvt, Wot, Wu1t, Wu2t);
  hipMemsetAsync(incom, 0, 4194304, stream);
  // G1: X @ [Wm1|Wgt1|Wg|Wk]
  gemm_kernel<4,1><<<dim3(256,7), 256, 0, stream>>>(Xb, 256, W1t, 256, bm1, bgt1, h1g1, 896,
                                                    nullptr, nullptr, nullptr, nullptr);
  route_kernel<<<8192, 256, 0, stream>>>(h1g1, Wgt2, bgt2, idxb, gateb);
  // G2: h1 @ Wm2 -> *gate -> scatter-add incoming
  gemm_kernel<4,2><<<dim3(256,2), 256, 0, stream>>>(h1g1, 896, W2t, 512, bm2, nullptr, nullptr, 0,
                                                    gateb, idxb, incom, nullptr);
  // qkv
  gemm_kernel<2,3><<<dim3(64,6), 256, 0, stream>>>(Sb, 256, Wqkvt, 256, bqkv, nullptr, qkvb, 768,
                                                   nullptr, nullptr, nullptr, nullptr);
  attn_kernel<<<1024, 256, 0, stream>>>(qkvb, obuf);
  // o @ Wo
  gemm_kernel<2,4><<<dim3(64,2), 256, 0, stream>>>(obuf, 256, Wot, 256, bo, nullptr, o2, 256,
                                                   nullptr, nullptr, nullptr, nullptr);
  ln1_kernel<<<1024, 256, 0, stream>>>(S, o2, incom, alng, alnb, S1f, A4);
  // update MLP
  gemm_kernel<2,5><<<dim3(64,4), 256, 0, stream>>>(A4, 512, Wu1t, 512, bu1, nullptr, U, 512,
                                                   nullptr, nullptr, nullptr, nullptr);
  gemm_kernel<2,6><<<dim3(64,2), 256, 0, stream>>>(U, 512, Wu2t, 512, bu2, nullptr, S2, 256,
                                                   nullptr, nullptr, nullptr, S1f);
  ln2_kernel<<<1024, 256, 0, stream>>>(S2, lng, lnb, (float*)d_out);
}

// Round 3
// 294.148 us; speedup vs baseline: 1.3297x; 1.3297x over previous
//
#include <hip/hip_runtime.h>

typedef __bf16 bf16_t;
typedef __bf16 bf16x8 __attribute__((ext_vector_type(8)));
typedef __bf16 bf16x4v __attribute__((ext_vector_type(4)));
typedef __bf16 bf16x2v __attribute__((ext_vector_type(2)));
typedef float f32x4 __attribute__((ext_vector_type(4)));

#define LN_EPS 1e-5f

// A&S 7.1.26 erf (|err|<=1.5e-7), branch-free
__device__ __forceinline__ float gelu_f(float x) {
  const float xs = x * 0.70710678118654752f;
  const float ax = fabsf(xs);
  const float t = __builtin_amdgcn_rcpf(fmaf(0.3275911f, ax, 1.0f));
  float y = fmaf(t, 1.061405429f, -1.453152027f);
  y = fmaf(t, y, 1.421413741f);
  y = fmaf(t, y, -0.284496736f);
  y = fmaf(t, y, 0.254829592f);
  y *= t;
  const float e = __expf(-ax * ax);
  const float er = fmaf(-y, e, 1.0f);          // erf(|xs|)
  return 0.5f * x * (1.0f + copysignf(er, xs));
}

__device__ __forceinline__ void async16(const bf16_t* g, bf16_t* l) {
  __builtin_amdgcn_global_load_lds(
      (const __attribute__((address_space(1))) void*)g,
      (__attribute__((address_space(3))) void*)l, 16, 0, 0);
}

// ---------------------------------------------------------------------------
// prep: X,S -> bf16 ; weights -> transposed (N-major) bf16
// ---------------------------------------------------------------------------
__global__ __launch_bounds__(256)
void prep_kernel(const float* __restrict__ X, const float* __restrict__ S,
                 const float* __restrict__ Wg, const float* __restrict__ Wk,
                 const float* __restrict__ Wm1, const float* __restrict__ Wgt1,
                 const float* __restrict__ Wm2, const float* __restrict__ Wqkv,
                 const float* __restrict__ Wo, const float* __restrict__ Wu1,
                 const float* __restrict__ Wu2,
                 bf16_t* __restrict__ Xb, bf16_t* __restrict__ Sb,
                 bf16_t* __restrict__ W1t, bf16_t* __restrict__ W2t,
                 bf16_t* __restrict__ Wqkvt, bf16_t* __restrict__ Wot,
                 bf16_t* __restrict__ Wu1t, bf16_t* __restrict__ Wu2t)
{
  const int bid = blockIdx.x;
  const int t = threadIdx.x;
  if (bid < 8192) {                       // X
    const int i = bid * 256 + t;
    const float4 v = ((const float4*)X)[i];
    bf16x4v o; o[0]=(bf16_t)v.x; o[1]=(bf16_t)v.y; o[2]=(bf16_t)v.z; o[3]=(bf16_t)v.w;
    ((bf16x4v*)Xb)[i] = o;
  } else if (bid < 9216) {                // S
    const int i = (bid - 8192) * 256 + t;
    const float4 v = ((const float4*)S)[i];
    bf16x4v o; o[0]=(bf16_t)v.x; o[1]=(bf16_t)v.y; o[2]=(bf16_t)v.z; o[3]=(bf16_t)v.w;
    ((bf16x4v*)Sb)[i] = o;
  } else if (bid < 10112) {               // W1t: 896 rows x 256
    const int n = bid - 9216;
    const int k = t;
    float v;
    if (n < 512)      v = Wm1[k * 512 + n];
    else if (n < 768) v = Wgt1[k * 256 + (n - 512)];
    else if (n < 832) v = Wg[k * 64 + (n - 768)];
    else if (n < 840) v = Wk[k * 8 + (n - 832)];
    else              v = 0.f;
    W1t[n * 256 + k] = (bf16_t)v;
  } else if (bid < 10368) {               // W2t: 256 rows x 512
    const int n = bid - 10112;
    for (int k = t; k < 512; k += 256) W2t[n * 512 + k] = (bf16_t)Wm2[k * 256 + n];
  } else if (bid < 11136) {               // Wqkvt: 768 x 256
    const int n = bid - 10368;
    Wqkvt[n * 256 + t] = (bf16_t)Wqkv[t * 768 + n];
  } else if (bid < 11392) {               // Wot: 256 x 256
    const int n = bid - 11136;
    Wot[n * 256 + t] = (bf16_t)Wo[t * 256 + n];
  } else if (bid < 11904) {               // Wu1t: 512 x 512
    const int n = bid - 11392;
    for (int k = t; k < 512; k += 256) Wu1t[n * 512 + k] = (bf16_t)Wu1[k * 512 + n];
  } else {                                // Wu2t: 256 x 512
    const int n = bid - 11904;
    for (int k = t; k < 512; k += 256) Wu2t[n * 512 + k] = (bf16_t)Wu2[k * 256 + n];
  }
}

// ---------------------------------------------------------------------------
// bf16 MFMA GEMM: C[M x N] = A[M x K] * Bt[N x K]^T, tile BMx128
// MFMA operands SWAPPED: lane's 4 acc regs = 4 consecutive cols of one row.
// EPI: 1=gelu(+bm1/bgt1)->bf16 (raw for col>=768)   3=+bias->bf16
//      4=+bias->f32   5=gelu(+bias)->bf16   6=+bias+resid->f32
//      7=+sumgate[row]*bias->f32  (incoming = H@Wm2 + sumgate*bm2)
// ---------------------------------------------------------------------------
template<int MT, int EPI>
__global__ __launch_bounds__(256)
void gemm_kernel(const bf16_t* __restrict__ A, int lda,
                 const bf16_t* __restrict__ Bt, int K,
                 const float* __restrict__ bias, const float* __restrict__ bias2,
                 void* __restrict__ outp, int ldc,
                 const float* __restrict__ gate, const float* __restrict__ resid)
{
  constexpr int BM = MT * 32;
  constexpr int IA = (BM * 4) / 256;
  const int m0 = blockIdx.x * BM;
  const int n0 = blockIdx.y * 128;
  const int t = threadIdx.x;
  const int w = t >> 6;
  const int lane = t & 63;
  const int wr = w >> 1, wc = w & 1;
  const int quad = lane >> 4, l15 = lane & 15;

  __shared__ bf16_t lA[BM * 32];
  __shared__ bf16_t lB[128 * 32];

  f32x4 acc[MT][4];
#pragma unroll
  for (int mt = 0; mt < MT; ++mt)
#pragma unroll
    for (int nt = 0; nt < 4; ++nt)
      acc[mt][nt] = (f32x4){0.f, 0.f, 0.f, 0.f};

  for (int k0 = 0; k0 < K; k0 += 32) {
#pragma unroll
    for (int i = 0; i < IA; ++i) {
      const int c = i * 256 + t;
      async16(A + (size_t)(m0 + (c >> 2)) * lda + k0 + (c & 3) * 8,
              lA + (size_t)(i * 256 + (t & 192)) * 8);
    }
#pragma unroll
    for (int i = 0; i < 2; ++i) {
      const int c = i * 256 + t;
      async16(Bt + (size_t)(n0 + (c >> 2)) * K + k0 + (c & 3) * 8,
              lB + (size_t)(i * 256 + (t & 192)) * 8);
    }
    __syncthreads();
    bf16x8 af[MT], bfr[4];
    const int ko = quad * 8;
#pragma unroll
    for (int mt = 0; mt < MT; ++mt)
      af[mt] = *(const bf16x8*)&lA[(wr * MT * 16 + mt * 16 + l15) * 32 + ko];
#pragma unroll
    for (int nt = 0; nt < 4; ++nt)
      bfr[nt] = *(const bf16x8*)&lB[(wc * 64 + nt * 16 + l15) * 32 + ko];
#pragma unroll
    for (int mt = 0; mt < MT; ++mt)
#pragma unroll
      for (int nt = 0; nt < 4; ++nt)
        acc[mt][nt] = __builtin_amdgcn_mfma_f32_16x16x32_bf16(bfr[nt], af[mt], acc[mt][nt], 0, 0, 0);
    __syncthreads();
  }

#pragma unroll
  for (int mt = 0; mt < MT; ++mt) {
    const int row = m0 + wr * MT * 16 + mt * 16 + l15;
    float gt = 0.f;
    if constexpr (EPI == 7) gt = gate[row];
#pragma unroll
    for (int nt = 0; nt < 4; ++nt) {
      const int colb = n0 + wc * 64 + nt * 16 + quad * 4;
      float v0 = acc[mt][nt][0], v1 = acc[mt][nt][1];
      float v2 = acc[mt][nt][2], v3 = acc[mt][nt][3];
      if constexpr (EPI == 1) {
        if (colb < 768) {
          const float* bp = (colb < 512) ? (bias + colb) : (bias2 + (colb - 512));
          const float4 bb = *(const float4*)bp;
          v0 = gelu_f(v0 + bb.x); v1 = gelu_f(v1 + bb.y);
          v2 = gelu_f(v2 + bb.z); v3 = gelu_f(v3 + bb.w);
        }
        bf16x4v o; o[0]=(bf16_t)v0; o[1]=(bf16_t)v1; o[2]=(bf16_t)v2; o[3]=(bf16_t)v3;
        *(bf16x4v*)&((bf16_t*)outp)[(size_t)row * ldc + colb] = o;
      } else if constexpr (EPI == 3) {
        const float4 bb = *(const float4*)&bias[colb];
        bf16x4v o; o[0]=(bf16_t)(v0+bb.x); o[1]=(bf16_t)(v1+bb.y);
        o[2]=(bf16_t)(v2+bb.z); o[3]=(bf16_t)(v3+bb.w);
        *(bf16x4v*)&((bf16_t*)outp)[(size_t)row * ldc + colb] = o;
      } else if constexpr (EPI == 4) {
        const float4 bb = *(const float4*)&bias[colb];
        float4 o = make_float4(v0+bb.x, v1+bb.y, v2+bb.z, v3+bb.w);
        *(float4*)&((float*)outp)[(size_t)row * ldc + colb] = o;
      } else if constexpr (EPI == 5) {
        const float4 bb = *(const float4*)&bias[colb];
        bf16x4v o; o[0]=(bf16_t)gelu_f(v0+bb.x); o[1]=(bf16_t)gelu_f(v1+bb.y);
        o[2]=(bf16_t)gelu_f(v2+bb.z); o[3]=(bf16_t)gelu_f(v3+bb.w);
        *(bf16x4v*)&((bf16_t*)outp)[(size_t)row * ldc + colb] = o;
      } else if constexpr (EPI == 6) {
        const float4 bb = *(const float4*)&bias[colb];
        const float4 rr = *(const float4*)&resid[(size_t)row * ldc + colb];
        float4 o = make_float4(v0+bb.x+rr.x, v1+bb.y+rr.y, v2+bb.z+rr.z, v3+bb.w+rr.w);
        *(float4*)&((float*)outp)[(size_t)row * ldc + colb] = o;
      } else {  // EPI 7
        const float4 bb = *(const float4*)&bias[colb];
        float4 o = make_float4(v0 + gt*bb.x, v1 + gt*bb.y, v2 + gt*bb.z, v3 + gt*bb.w);
        *(float4*)&((float*)outp)[(size_t)row * ldc + colb] = o;
      }
    }
  }
}

// ---------------------------------------------------------------------------
// route: gate = sigmoid(g1.Wgt2 + bgt2); idx = argmax(g)*8 + argmax(k)
// also counts tokens per (batch,slot) for the counting-sort
// ---------------------------------------------------------------------------
__global__ __launch_bounds__(256)
void route_kernel(const bf16_t* __restrict__ h1g1, const float* __restrict__ Wgt2,
                  const float* __restrict__ bgt2, int* __restrict__ idxb,
                  float* __restrict__ gateb, int* __restrict__ counts)
{
  const int w = threadIdx.x >> 6, lane = threadIdx.x & 63;
  const int m = blockIdx.x * 4 + w;
  const bf16_t* rowp = h1g1 + (size_t)m * 896;

  bf16x4v g4 = *(const bf16x4v*)&rowp[512 + lane * 4];
  float s = 0.f;
#pragma unroll
  for (int j = 0; j < 4; ++j) s += (float)g4[j] * Wgt2[lane * 4 + j];
#pragma unroll
  for (int off = 32; off; off >>= 1) s += __shfl_xor(s, off, 64);
  const float gate = 1.0f / (1.0f + __expf(-(s + bgt2[0])));

  float vg = (float)rowp[768 + lane];
  int ig = lane;
#pragma unroll
  for (int off = 32; off; off >>= 1) {
    const float ov = __shfl_xor(vg, off, 64);
    const int oi = __shfl_xor(ig, off, 64);
    if (ov > vg || (ov == vg && oi < ig)) { vg = ov; ig = oi; }
  }
  float vk = (lane < 8) ? (float)rowp[832 + lane] : -1e30f;
  int ik = lane;
#pragma unroll
  for (int off = 32; off; off >>= 1) {
    const float ov = __shfl_xor(vk, off, 64);
    const int oi = __shfl_xor(ik, off, 64);
    if (ov > vk || (ov == vk && oi < ik)) { vk = ov; ik = oi; }
  }
  if (lane == 0) {
    const int idx = ig * 8 + ik;
    idxb[m] = idx;
    gateb[m] = gate;
    atomicAdd(&counts[(m >> 12) * 512 + idx], 1);
  }
}

// exclusive scan of 4096 ints, single block of 1024
__global__ __launch_bounds__(1024)
void scan_kernel(const int* __restrict__ counts, int* __restrict__ offsets)
{
  __shared__ int tmp[1024];
  const int t = threadIdx.x;
  const int4 c = ((const int4*)counts)[t];
  const int s = c.x + c.y + c.z + c.w;
  tmp[t] = s;
  __syncthreads();
  for (int off = 1; off < 1024; off <<= 1) {
    const int v = (t >= off) ? tmp[t - off] : 0;
    __syncthreads();
    tmp[t] += v;
    __syncthreads();
  }
  const int excl = tmp[t] - s;
  int4 o; o.x = excl; o.y = excl + c.x; o.z = o.y + c.y; o.w = o.z + c.z;
  ((int4*)offsets)[t] = o;
}

__global__ __launch_bounds__(256)
void fill_kernel(const int* __restrict__ idxb, const int* __restrict__ offsets,
                 int* __restrict__ cursor, int* __restrict__ perm)
{
  const int l = blockIdx.x * 256 + threadIdx.x;
  const int bs = (l >> 12) * 512 + idxb[l];
  const int pos = atomicAdd(&cursor[bs], 1);
  perm[offsets[bs] + pos] = l;
}

// gather: H[b,slot,:] = sum_{tokens} gate_l * gelu_h1[l,:]; sumg = sum gate
__global__ __launch_bounds__(256)
void gather_kernel(const bf16_t* __restrict__ h1g1, const float* __restrict__ gateb,
                   const int* __restrict__ perm, const int* __restrict__ offsets,
                   const int* __restrict__ counts, bf16_t* __restrict__ H,
                   float* __restrict__ sumg)
{
  const int bs = blockIdx.x;
  const int t = threadIdx.x;
  const int start = offsets[bs];
  const int cnt = counts[bs];
  float a0 = 0.f, a1 = 0.f, sg = 0.f;
  for (int i = 0; i < cnt; ++i) {
    const int l = perm[start + i];
    const float g = gateb[l];
    const bf16x2v hv = *(const bf16x2v*)&h1g1[(size_t)l * 896 + t * 2];
    a0 = fmaf(g, (float)hv[0], a0);
    a1 = fmaf(g, (float)hv[1], a1);
    sg += g;
  }
  bf16x2v o; o[0] = (bf16_t)a0; o[1] = (bf16_t)a1;
  *(bf16x2v*)&H[(size_t)bs * 512 + t * 2] = o;
  if (t == 0) sumg[bs] = sg;
}

// ---------------------------------------------------------------------------
// fused slot attention: block = (b, h, 32-query chunk)
// ---------------------------------------------------------------------------
__global__ __launch_bounds__(256)
void attn_kernel(const bf16_t* __restrict__ qkv, bf16_t* __restrict__ obuf)
{
  const int bid = blockIdx.x;
  const int qc = bid & 15;
  const int h = (bid >> 4) & 7;
  const int b = bid >> 7;
  const int t = threadIdx.x;
  const int w = t >> 6, lane = t & 63;
  const int quad = lane >> 4, l15 = lane & 15;

  __shared__ bf16_t sP[32 * 520];
  __shared__ bf16_t sVt[32 * 264];
  __shared__ float sL[32];

  bf16x8 qf[2];
#pragma unroll
  for (int mt = 0; mt < 2; ++mt) {
    const int row = b * 512 + qc * 32 + mt * 16 + l15;
    qf[mt] = *(const bf16x8*)&qkv[(size_t)row * 768 + h * 32 + quad * 8];
  }
  const float scale = 0.17677669529663687f;  // 1/sqrt(32)
  for (int kt = w; kt < 32; kt += 4) {
    const int key = b * 512 + kt * 16 + l15;
    const bf16x8 kf = *(const bf16x8*)&qkv[(size_t)key * 768 + 256 + h * 32 + quad * 8];
#pragma unroll
    for (int mt = 0; mt < 2; ++mt) {
      f32x4 c = (f32x4){0.f, 0.f, 0.f, 0.f};
      c = __builtin_amdgcn_mfma_f32_16x16x32_bf16(qf[mt], kf, c, 0, 0, 0);
#pragma unroll
      for (int r = 0; r < 4; ++r)
        sP[(mt * 16 + quad * 4 + r) * 520 + kt * 16 + l15] = (bf16_t)(c[r] * scale);
    }
  }
  __syncthreads();

#pragma unroll
  for (int ri = 0; ri < 8; ++ri) {
    const int row = w * 8 + ri;
    const bf16x8 sv = *(const bf16x8*)&sP[row * 520 + lane * 8];
    float sval[8];
    float mx = -1e30f;
#pragma unroll
    for (int j = 0; j < 8; ++j) { sval[j] = (float)sv[j]; mx = fmaxf(mx, sval[j]); }
#pragma unroll
    for (int off = 32; off; off >>= 1) mx = fmaxf(mx, __shfl_xor(mx, off, 64));
    float sum = 0.f;
    bf16x8 pv;
#pragma unroll
    for (int j = 0; j < 8; ++j) { const float e = __expf(sval[j] - mx); sum += e; pv[j] = (bf16_t)e; }
#pragma unroll
    for (int off = 32; off; off >>= 1) sum += __shfl_xor(sum, off, 64);
    *(bf16x8*)&sP[row * 520 + lane * 8] = pv;
    if (lane == 0) sL[row] = sum;
  }
  __syncthreads();

  const int omt = w >> 1, ont = w & 1;
  f32x4 oacc = (f32x4){0.f, 0.f, 0.f, 0.f};
  for (int half = 0; half < 2; ++half) {
    if (half) __syncthreads();
#pragma unroll
    for (int i = 0; i < 32; ++i) {
      const int el = i * 256 + t;
      const int dh = el & 31, key = el >> 5;
      sVt[dh * 264 + key] = qkv[(size_t)(b * 512 + half * 256 + key) * 768 + 512 + h * 32 + dh];
    }
    __syncthreads();
#pragma unroll
    for (int kt = 0; kt < 8; ++kt) {
      const bf16x8 af = *(const bf16x8*)&sP[(omt * 16 + l15) * 520 + half * 256 + kt * 32 + quad * 8];
      const bf16x8 vf = *(const bf16x8*)&sVt[(ont * 16 + l15) * 264 + kt * 32 + quad * 8];
      oacc = __builtin_amdgcn_mfma_f32_16x16x32_bf16(af, vf, oacc, 0, 0, 0);
    }
  }
#pragma unroll
  for (int r = 0; r < 4; ++r) {
    const int row = omt * 16 + quad * 4 + r;
    const float val = oacc[r] / sL[row];
    obuf[(size_t)(b * 512 + qc * 32 + row) * 256 + h * 32 + ont * 16 + l15] = (bf16_t)val;
  }
}

// ---------------------------------------------------------------------------
__global__ __launch_bounds__(256)
void ln1_kernel(const float* __restrict__ S, const float* __restrict__ o2,
                const float* __restrict__ incom, const float* __restrict__ g,
                const float* __restrict__ bb, float* __restrict__ S1f,
                bf16_t* __restrict__ A4)
{
  const int w = threadIdx.x >> 6, lane = threadIdx.x & 63;
  const int row = blockIdx.x * 4 + w;
  const size_t base = (size_t)row * 256 + lane * 4;
  const float4 xs = *(const float4*)&S[base];
  const float4 xo = *(const float4*)&o2[base];
  float x[4] = {xs.x + xo.x, xs.y + xo.y, xs.z + xo.z, xs.w + xo.w};
  float sum = x[0] + x[1] + x[2] + x[3];
  float sq = x[0]*x[0] + x[1]*x[1] + x[2]*x[2] + x[3]*x[3];
#pragma unroll
  for (int off = 32; off; off >>= 1) { sum += __shfl_xor(sum, off, 64); sq += __shfl_xor(sq, off, 64); }
  const float mean = sum * 0.00390625f;
  const float var = sq * 0.00390625f - mean * mean;
  const float rstd = rsqrtf(var + LN_EPS);
  const float4 gg = *(const float4*)&g[lane * 4];
  const float4 bv = *(const float4*)&bb[lane * 4];
  float y[4];
  y[0] = (x[0]-mean)*rstd*gg.x + bv.x;
  y[1] = (x[1]-mean)*rstd*gg.y + bv.y;
  y[2] = (x[2]-mean)*rstd*gg.z + bv.z;
  y[3] = (x[3]-mean)*rstd*gg.w + bv.w;
  *(float4*)&S1f[base] = make_float4(y[0], y[1], y[2], y[3]);
  bf16x4v yb; yb[0]=(bf16_t)y[0]; yb[1]=(bf16_t)y[1]; yb[2]=(bf16_t)y[2]; yb[3]=(bf16_t)y[3];
  *(bf16x4v*)&A4[(size_t)row * 512 + lane * 4] = yb;
  const float4 ic = *(const float4*)&incom[base];
  bf16x4v ib; ib[0]=(bf16_t)ic.x; ib[1]=(bf16_t)ic.y; ib[2]=(bf16_t)ic.z; ib[3]=(bf16_t)ic.w;
  *(bf16x4v*)&A4[(size_t)row * 512 + 256 + lane * 4] = ib;
}

__global__ __launch_bounds__(256)
void ln2_kernel(const float* __restrict__ S2, const float* __restrict__ g,
                const float* __restrict__ bb, float* __restrict__ out)
{
  const int w = threadIdx.x >> 6, lane = threadIdx.x & 63;
  const int row = blockIdx.x * 4 + w;
  const size_t base = (size_t)row * 256 + lane * 4;
  const float4 xv = *(const float4*)&S2[base];
  float x[4] = {xv.x, xv.y, xv.z, xv.w};
  float sum = x[0] + x[1] + x[2] + x[3];
  float sq = x[0]*x[0] + x[1]*x[1] + x[2]*x[2] + x[3]*x[3];
#pragma unroll
  for (int off = 32; off; off >>= 1) { sum += __shfl_xor(sum, off, 64); sq += __shfl_xor(sq, off, 64); }
  const float mean = sum * 0.00390625f;
  const float var = sq * 0.00390625f - mean * mean;
  const float rstd = rsqrtf(var + LN_EPS);
  const float4 gg = *(const float4*)&g[lane * 4];
  const float4 bv = *(const float4*)&bb[lane * 4];
  float4 o;
  o.x = (x[0]-mean)*rstd*gg.x + bv.x;
  o.y = (x[1]-mean)*rstd*gg.y + bv.y;
  o.z = (x[2]-mean)*rstd*gg.z + bv.z;
  o.w = (x[3]-mean)*rstd*gg.w + bv.w;
  *(float4*)&out[base] = o;
}

// ---------------------------------------------------------------------------
extern "C" void kernel_launch(void* const* d_in, const int* in_sizes, int n_in,
                              void* d_out, int out_size, void* d_ws, size_t ws_size,
                              hipStream_t stream)
{
  (void)in_sizes; (void)n_in; (void)out_size; (void)ws_size;
  const float* X    = (const float*)d_in[0];
  const float* S    = (const float*)d_in[1];
  const float* Wg   = (const float*)d_in[2];
  const float* Wk   = (const float*)d_in[3];
  const float* Wm1  = (const float*)d_in[4];
  const float* bm1  = (const float*)d_in[5];
  const float* Wm2  = (const float*)d_in[6];
  const float* bm2  = (const float*)d_in[7];
  const float* Wgt1 = (const float*)d_in[8];
  const float* bgt1 = (const float*)d_in[9];
  const float* Wgt2 = (const float*)d_in[10];
  const float* bgt2 = (const float*)d_in[11];
  const float* Wqkv = (const float*)d_in[12];
  const float* bqkv = (const float*)d_in[13];
  const float* Wo   = (const float*)d_in[14];
  const float* bo   = (const float*)d_in[15];
  const float* alng = (const float*)d_in[16];
  const float* alnb = (const float*)d_in[17];
  const float* Wu1  = (const float*)d_in[18];
  const float* bu1  = (const float*)d_in[19];
  const float* Wu2  = (const float*)d_in[20];
  const float* bu2  = (const float*)d_in[21];
  const float* lng  = (const float*)d_in[22];
  const float* lnb  = (const float*)d_in[23];

  char* p = (char*)d_ws;
  auto carve = [&](size_t bytes) { char* r = p; p += bytes; return r; };
  bf16_t* Xb    = (bf16_t*)carve(16777216);   // 32768 x 256
  bf16_t* Sb    = (bf16_t*)carve(2097152);    // 4096 x 256
  bf16_t* W1t   = (bf16_t*)carve(458752);     // 896 x 256
  bf16_t* W2t   = (bf16_t*)carve(262144);     // 256 x 512
  bf16_t* Wqkvt = (bf16_t*)carve(393216);     // 768 x 256
  bf16_t* Wot   = (bf16_t*)carve(131072);     // 256 x 256
  bf16_t* Wu1t  = (bf16_t*)carve(524288);     // 512 x 512
  bf16_t* Wu2t  = (bf16_t*)carve(262144);     // 256 x 512
  bf16_t* h1g1  = (bf16_t*)carve(58720256);   // 32768 x 896
  int*    idxb  = (int*)carve(131072);
  float*  gateb = (float*)carve(131072);
  float*  incom = (float*)carve(4194304);     // 4096 x 256 f32
  bf16_t* qkvb  = (bf16_t*)carve(6291456);    // 4096 x 768
  bf16_t* obuf  = (bf16_t*)carve(2097152);    // 4096 x 256
  float*  o2    = (float*)carve(4194304);
  float*  S1f   = (float*)carve(4194304);
  bf16_t* A4    = (bf16_t*)carve(4194304);    // 4096 x 512
  bf16_t* U     = (bf16_t*)carve(4194304);    // 4096 x 512 (aliased by H)
  float*  S2    = (float*)carve(4194304);
  int*    counts  = (int*)carve(16384);       // 4096
  int*    offsets = (int*)carve(16384);
  int*    cursor  = (int*)carve(16384);
  int*    perm    = (int*)carve(131072);      // 32768
  float*  sumg    = (float*)carve(16384);
  bf16_t* H = U;  // disjoint lifetime: H dead before U written

  prep_kernel<<<12160, 256, 0, stream>>>(X, S, Wg, Wk, Wm1, Wgt1, Wm2, Wqkv, Wo, Wu1, Wu2,
                                         Xb, Sb, W1t, W2t, Wqkvt, Wot, Wu1t, Wu2t);
  hipMemsetAsync(counts, 0, 16384, stream);
  hipMemsetAsync(cursor, 0, 16384, stream);
  // G1: X @ [Wm1|Wgt1|Wg|Wk]
  gemm_kernel<4,1><<<dim3(256,7), 256, 0, stream>>>(Xb, 256, W1t, 256, bm1, bgt1, h1g1, 896,
                                                    nullptr, nullptr);
  route_kernel<<<8192, 256, 0, stream>>>(h1g1, Wgt2, bgt2, idxb, gateb, counts);
  scan_kernel<<<1, 1024, 0, stream>>>(counts, offsets);
  fill_kernel<<<128, 256, 0, stream>>>(idxb, offsets, cursor, perm);
  gather_kernel<<<4096, 256, 0, stream>>>(h1g1, gateb, perm, offsets, counts, H, sumg);
  // incoming = H @ Wm2 + sumgate * bm2
  gemm_kernel<2,7><<<dim3(64,2), 256, 0, stream>>>(H, 512, W2t, 512, bm2, nullptr, incom, 256,
                                                   sumg, nullptr);
  // qkv
  gemm_kernel<2,3><<<dim3(64,6), 256, 0, stream>>>(Sb, 256, Wqkvt, 256, bqkv, nullptr, qkvb, 768,
                                                   nullptr, nullptr);
  attn_kernel<<<1024, 256, 0, stream>>>(qkvb, obuf);
  // o @ Wo
  gemm_kernel<2,4><<<dim3(64,2), 256, 0, stream>>>(obuf, 256, Wot, 256, bo, nullptr, o2, 256,
                                                   nullptr, nullptr);
  ln1_kernel<<<1024, 256, 0, stream>>>(S, o2, incom, alng, alnb, S1f, A4);
  // update MLP
  gemm_kernel<2,5><<<dim3(64,4), 256, 0, stream>>>(A4, 512, Wu1t, 512, bu1, nullptr, U, 512,
                                                   nullptr, nullptr);
  gemm_kernel<2,6><<<dim3(64,2), 256, 0, stream>>>(U, 512, Wu2t, 512, bu2, nullptr, S2, 256,
                                                   nullptr, S1f);
  ln2_kernel<<<1024, 256, 0, stream>>>(S2, lng, lnb, (float*)d_out);
}

// Round 4
// 289.837 us; speedup vs baseline: 1.3495x; 1.0149x over previous
//
#include <hip/hip_runtime.h>

typedef __bf16 bf16_t;
typedef __bf16 bf16x8 __attribute__((ext_vector_type(8)));
typedef __bf16 bf16x4v __attribute__((ext_vector_type(4)));
typedef __bf16 bf16x2v __attribute__((ext_vector_type(2)));
typedef float f32x4 __attribute__((ext_vector_type(4)));

#define LN_EPS 1e-5f

// njuffa's 1-ulp erff (branchy; fast path for |a|<=0.921875 is 6 fma)
__device__ __forceinline__ float erf_fast(float a) {
  const float t = fabsf(a);
  const float s = a * a;
  float r;
  if (t > 0.921875f) {
    float u;
    r = fmaf(-1.72853470e-5f, t, 3.83197126e-4f);
    u = fmaf(-3.88396438e-3f, t, 2.42546219e-2f);
    r = fmaf(r, s, u);
    r = fmaf(r, t, 1.06777877e-1f);
    r = fmaf(r, t, -6.37245935e-1f);
    r = fmaf(r, t, -1.28717512e-1f);
    r = fmaf(r, t, t);
    r = 1.0f - __expf(-r * 1.442695041f * 0.693147181f);  // expf(-r)
    r = copysignf(r, a);
  } else {
    r = -5.96761703e-4f;
    r = fmaf(r, s, 4.99119423e-3f);
    r = fmaf(r, s, -2.67681349e-2f);
    r = fmaf(r, s, 1.12819925e-1f);
    r = fmaf(r, s, -3.76125336e-1f);
    r = fmaf(r, s, 1.28379166e-1f);
    r = fmaf(r, a, a);
  }
  return r;
}

__device__ __forceinline__ float gelu_f(float x) {
  const float h = 0.5f * x;
  return fmaf(h, erf_fast(x * 0.70710678118654752f), h);
}

__device__ __forceinline__ void async16(const bf16_t* g, bf16_t* l) {
  __builtin_amdgcn_global_load_lds(
      (const __attribute__((address_space(1))) void*)g,
      (__attribute__((address_space(3))) void*)l, 16, 0, 0);
}

// ---------------------------------------------------------------------------
// prep: X,S -> bf16 ; weights -> transposed (N-major) bf16
// ---------------------------------------------------------------------------
__global__ __launch_bounds__(256)
void prep_kernel(const float* __restrict__ X, const float* __restrict__ S,
                 const float* __restrict__ Wg, const float* __restrict__ Wk,
                 const float* __restrict__ Wm1, const float* __restrict__ Wgt1,
                 const float* __restrict__ Wm2, const float* __restrict__ Wqkv,
                 const float* __restrict__ Wo, const float* __restrict__ Wu1,
                 const float* __restrict__ Wu2,
                 bf16_t* __restrict__ Xb, bf16_t* __restrict__ Sb,
                 bf16_t* __restrict__ W1t, bf16_t* __restrict__ W2t,
                 bf16_t* __restrict__ Wqkvt, bf16_t* __restrict__ Wot,
                 bf16_t* __restrict__ Wu1t, bf16_t* __restrict__ Wu2t)
{
  const int bid = blockIdx.x;
  const int t = threadIdx.x;
  if (bid < 8192) {                       // X
    const int i = bid * 256 + t;
    const float4 v = ((const float4*)X)[i];
    bf16x4v o; o[0]=(bf16_t)v.x; o[1]=(bf16_t)v.y; o[2]=(bf16_t)v.z; o[3]=(bf16_t)v.w;
    ((bf16x4v*)Xb)[i] = o;
  } else if (bid < 9216) {                // S
    const int i = (bid - 8192) * 256 + t;
    const float4 v = ((const float4*)S)[i];
    bf16x4v o; o[0]=(bf16_t)v.x; o[1]=(bf16_t)v.y; o[2]=(bf16_t)v.z; o[3]=(bf16_t)v.w;
    ((bf16x4v*)Sb)[i] = o;
  } else if (bid < 10112) {               // W1t: 896 rows x 256
    const int n = bid - 9216;
    const int k = t;
    float v;
    if (n < 512)      v = Wm1[k * 512 + n];
    else if (n < 768) v = Wgt1[k * 256 + (n - 512)];
    else if (n < 832) v = Wg[k * 64 + (n - 768)];
    else if (n < 840) v = Wk[k * 8 + (n - 832)];
    else              v = 0.f;
    W1t[n * 256 + k] = (bf16_t)v;
  } else if (bid < 10368) {               // W2t: 256 rows x 512
    const int n = bid - 10112;
    for (int k = t; k < 512; k += 256) W2t[n * 512 + k] = (bf16_t)Wm2[k * 256 + n];
  } else if (bid < 11136) {               // Wqkvt: 768 x 256
    const int n = bid - 10368;
    Wqkvt[n * 256 + t] = (bf16_t)Wqkv[t * 768 + n];
  } else if (bid < 11392) {               // Wot: 256 x 256
    const int n = bid - 11136;
    Wot[n * 256 + t] = (bf16_t)Wo[t * 256 + n];
  } else if (bid < 11904) {               // Wu1t: 512 x 512
    const int n = bid - 11392;
    for (int k = t; k < 512; k += 256) Wu1t[n * 512 + k] = (bf16_t)Wu1[k * 512 + n];
  } else {                                // Wu2t: 256 x 512
    const int n = bid - 11904;
    for (int k = t; k < 512; k += 256) Wu2t[n * 512 + k] = (bf16_t)Wu2[k * 256 + n];
  }
}

// ---------------------------------------------------------------------------
// bf16 MFMA GEMM: C[M x N] = A[M x K] * Bt[N x K]^T, tile (MT*32) x 128, BK=64
// LDS stored with XOR k-chunk swizzle: physical chunk = logical ^ (row&7)
// (keeps global_load_lds lane-linear, makes ds_read_b128 2-way-conflict only)
// MFMA operands swapped: lane's 4 acc regs = 4 consecutive cols of one row.
// EPI: 1=gelu(+bm1/bgt1)->bf16 (raw for col>=768)   3=+bias->bf16
//      4=+bias->f32   5=gelu(+bias)->bf16   6=+bias+resid->f32
//      7=+sumgate[row]*bias->f32
// ---------------------------------------------------------------------------
template<int MT, int EPI>
__global__ __launch_bounds__(256)
void gemm_kernel(const bf16_t* __restrict__ A, int lda,
                 const bf16_t* __restrict__ Bt, int K,
                 const float* __restrict__ bias, const float* __restrict__ bias2,
                 void* __restrict__ outp, int ldc,
                 const float* __restrict__ gate, const float* __restrict__ resid)
{
  constexpr int BM = MT * 32;
  constexpr int BK = 64;
  constexpr int IA = (BM * BK) / 2048;   // 16B chunks per 256-thread pass (A)
  constexpr int IB = (128 * BK) / 2048;  // = 4
  const int m0 = blockIdx.x * BM;
  const int n0 = blockIdx.y * 128;
  const int t = threadIdx.x;
  const int w = t >> 6;
  const int lane = t & 63;
  const int wr = w >> 1, wc = w & 1;
  const int quad = lane >> 4, l15 = lane & 15;

  __shared__ bf16_t lA[BM * BK];
  __shared__ bf16_t lB[128 * BK];

  f32x4 acc[MT][4];
#pragma unroll
  for (int mt = 0; mt < MT; ++mt)
#pragma unroll
    for (int nt = 0; nt < 4; ++nt)
      acc[mt][nt] = (f32x4){0.f, 0.f, 0.f, 0.f};

  for (int k0 = 0; k0 < K; k0 += BK) {
#pragma unroll
    for (int i = 0; i < IA; ++i) {
      const int c = i * 256 + t;
      const int row = c >> 3, p = c & 7;
      async16(A + (size_t)(m0 + row) * lda + k0 + ((p ^ (row & 7)) << 3),
              lA + (size_t)(i * 256 + (t & 192)) * 8);
    }
#pragma unroll
    for (int i = 0; i < IB; ++i) {
      const int c = i * 256 + t;
      const int row = c >> 3, p = c & 7;
      async16(Bt + (size_t)(n0 + row) * K + k0 + ((p ^ (row & 7)) << 3),
              lB + (size_t)(i * 256 + (t & 192)) * 8);
    }
    __syncthreads();
#pragma unroll
    for (int ksub = 0; ksub < 2; ++ksub) {
      bf16x8 af[MT], bfr[4];
#pragma unroll
      for (int mt = 0; mt < MT; ++mt) {
        const int row = wr * MT * 16 + mt * 16 + l15;
        af[mt] = *(const bf16x8*)&lA[row * BK + ((((ksub << 2) | quad) ^ (row & 7)) << 3)];
      }
#pragma unroll
      for (int nt = 0; nt < 4; ++nt) {
        const int row = wc * 64 + nt * 16 + l15;
        bfr[nt] = *(const bf16x8*)&lB[row * BK + ((((ksub << 2) | quad) ^ (row & 7)) << 3)];
      }
#pragma unroll
      for (int mt = 0; mt < MT; ++mt)
#pragma unroll
        for (int nt = 0; nt < 4; ++nt)
          acc[mt][nt] = __builtin_amdgcn_mfma_f32_16x16x32_bf16(bfr[nt], af[mt], acc[mt][nt], 0, 0, 0);
    }
    __syncthreads();
  }

#pragma unroll
  for (int mt = 0; mt < MT; ++mt) {
    const int row = m0 + wr * MT * 16 + mt * 16 + l15;
    float gt = 0.f;
    if constexpr (EPI == 7) gt = gate[row];
#pragma unroll
    for (int nt = 0; nt < 4; ++nt) {
      const int colb = n0 + wc * 64 + nt * 16 + quad * 4;
      float v0 = acc[mt][nt][0], v1 = acc[mt][nt][1];
      float v2 = acc[mt][nt][2], v3 = acc[mt][nt][3];
      if constexpr (EPI == 1) {
        if (colb < 768) {
          const float* bp = (colb < 512) ? (bias + colb) : (bias2 + (colb - 512));
          const float4 bb = *(const float4*)bp;
          v0 = gelu_f(v0 + bb.x); v1 = gelu_f(v1 + bb.y);
          v2 = gelu_f(v2 + bb.z); v3 = gelu_f(v3 + bb.w);
        }
        bf16x4v o; o[0]=(bf16_t)v0; o[1]=(bf16_t)v1; o[2]=(bf16_t)v2; o[3]=(bf16_t)v3;
        *(bf16x4v*)&((bf16_t*)outp)[(size_t)row * ldc + colb] = o;
      } else if constexpr (EPI == 3) {
        const float4 bb = *(const float4*)&bias[colb];
        bf16x4v o; o[0]=(bf16_t)(v0+bb.x); o[1]=(bf16_t)(v1+bb.y);
        o[2]=(bf16_t)(v2+bb.z); o[3]=(bf16_t)(v3+bb.w);
        *(bf16x4v*)&((bf16_t*)outp)[(size_t)row * ldc + colb] = o;
      } else if constexpr (EPI == 4) {
        const float4 bb = *(const float4*)&bias[colb];
        float4 o = make_float4(v0+bb.x, v1+bb.y, v2+bb.z, v3+bb.w);
        *(float4*)&((float*)outp)[(size_t)row * ldc + colb] = o;
      } else if constexpr (EPI == 5) {
        const float4 bb = *(const float4*)&bias[colb];
        bf16x4v o; o[0]=(bf16_t)gelu_f(v0+bb.x); o[1]=(bf16_t)gelu_f(v1+bb.y);
        o[2]=(bf16_t)gelu_f(v2+bb.z); o[3]=(bf16_t)gelu_f(v3+bb.w);
        *(bf16x4v*)&((bf16_t*)outp)[(size_t)row * ldc + colb] = o;
      } else if constexpr (EPI == 6) {
        const float4 bb = *(const float4*)&bias[colb];
        const float4 rr = *(const float4*)&resid[(size_t)row * ldc + colb];
        float4 o = make_float4(v0+bb.x+rr.x, v1+bb.y+rr.y, v2+bb.z+rr.z, v3+bb.w+rr.w);
        *(float4*)&((float*)outp)[(size_t)row * ldc + colb] = o;
      } else {  // EPI 7
        const float4 bb = *(const float4*)&bias[colb];
        float4 o = make_float4(v0 + gt*bb.x, v1 + gt*bb.y, v2 + gt*bb.z, v3 + gt*bb.w);
        *(float4*)&((float*)outp)[(size_t)row * ldc + colb] = o;
      }
    }
  }
}

// ---------------------------------------------------------------------------
// route: gate = sigmoid(g1.Wgt2 + bgt2); idx = argmax(g)*8 + argmax(k); counts
// ---------------------------------------------------------------------------
__global__ __launch_bounds__(256)
void route_kernel(const bf16_t* __restrict__ h1g1, const float* __restrict__ Wgt2,
                  const float* __restrict__ bgt2, int* __restrict__ idxb,
                  float* __restrict__ gateb, int* __restrict__ counts)
{
  const int w = threadIdx.x >> 6, lane = threadIdx.x & 63;
  const int m = blockIdx.x * 4 + w;
  const bf16_t* rowp = h1g1 + (size_t)m * 896;

  bf16x4v g4 = *(const bf16x4v*)&rowp[512 + lane * 4];
  float s = 0.f;
#pragma unroll
  for (int j = 0; j < 4; ++j) s += (float)g4[j] * Wgt2[lane * 4 + j];
#pragma unroll
  for (int off = 32; off; off >>= 1) s += __shfl_xor(s, off, 64);
  const float gate = 1.0f / (1.0f + __expf(-(s + bgt2[0])));

  float vg = (float)rowp[768 + lane];
  int ig = lane;
#pragma unroll
  for (int off = 32; off; off >>= 1) {
    const float ov = __shfl_xor(vg, off, 64);
    const int oi = __shfl_xor(ig, off, 64);
    if (ov > vg || (ov == vg && oi < ig)) { vg = ov; ig = oi; }
  }
  float vk = (lane < 8) ? (float)rowp[832 + lane] : -1e30f;
  int ik = lane;
#pragma unroll
  for (int off = 32; off; off >>= 1) {
    const float ov = __shfl_xor(vk, off, 64);
    const int oi = __shfl_xor(ik, off, 64);
    if (ov > vk || (ov == vk && oi < ik)) { vk = ov; ik = oi; }
  }
  if (lane == 0) {
    const int idx = ig * 8 + ik;
    idxb[m] = idx;
    gateb[m] = gate;
    atomicAdd(&counts[(m >> 12) * 512 + idx], 1);
  }
}

// exclusive scan of 4096 ints, single block of 1024
__global__ __launch_bounds__(1024)
void scan_kernel(const int* __restrict__ counts, int* __restrict__ offsets)
{
  __shared__ int tmp[1024];
  const int t = threadIdx.x;
  const int4 c = ((const int4*)counts)[t];
  const int s = c.x + c.y + c.z + c.w;
  tmp[t] = s;
  __syncthreads();
  for (int off = 1; off < 1024; off <<= 1) {
    const int v = (t >= off) ? tmp[t - off] : 0;
    __syncthreads();
    tmp[t] += v;
    __syncthreads();
  }
  const int excl = tmp[t] - s;
  int4 o; o.x = excl; o.y = excl + c.x; o.z = o.y + c.y; o.w = o.z + c.z;
  ((int4*)offsets)[t] = o;
}

__global__ __launch_bounds__(256)
void fill_kernel(const int* __restrict__ idxb, const int* __restrict__ offsets,
                 int* __restrict__ cursor, int* __restrict__ perm)
{
  const int l = blockIdx.x * 256 + threadIdx.x;
  const int bs = (l >> 12) * 512 + idxb[l];
  const int pos = atomicAdd(&cursor[bs], 1);
  perm[offsets[bs] + pos] = l;
}

// gather: H[b,slot,:] = sum_{tokens} gate_l * gelu_h1[l,:]; sumg = sum gate
__global__ __launch_bounds__(256)
void gather_kernel(const bf16_t* __restrict__ h1g1, const float* __restrict__ gateb,
                   const int* __restrict__ perm, const int* __restrict__ offsets,
                   const int* __restrict__ counts, bf16_t* __restrict__ H,
                   float* __restrict__ sumg)
{
  const int bs = blockIdx.x;
  const int t = threadIdx.x;
  const int start = offsets[bs];
  const int cnt = counts[bs];
  float a0 = 0.f, a1 = 0.f, sg = 0.f;
  for (int i = 0; i < cnt; ++i) {
    const int l = perm[start + i];
    const float g = gateb[l];
    const bf16x2v hv = *(const bf16x2v*)&h1g1[(size_t)l * 896 + t * 2];
    a0 = fmaf(g, (float)hv[0], a0);
    a1 = fmaf(g, (float)hv[1], a1);
    sg += g;
  }
  bf16x2v o; o[0] = (bf16_t)a0; o[1] = (bf16_t)a1;
  *(bf16x2v*)&H[(size_t)bs * 512 + t * 2] = o;
  if (t == 0) sumg[bs] = sg;
}

// ---------------------------------------------------------------------------
// fused slot attention: block = (b, h, 32-query chunk)
// ---------------------------------------------------------------------------
__global__ __launch_bounds__(256)
void attn_kernel(const bf16_t* __restrict__ qkv, bf16_t* __restrict__ obuf)
{
  const int bid = blockIdx.x;
  const int qc = bid & 15;
  const int h = (bid >> 4) & 7;
  const int b = bid >> 7;
  const int t = threadIdx.x;
  const int w = t >> 6, lane = t & 63;
  const int quad = lane >> 4, l15 = lane & 15;

  __shared__ bf16_t sP[32 * 520];
  __shared__ bf16_t sVt[32 * 264];
  __shared__ float sL[32];

  bf16x8 qf[2];
#pragma unroll
  for (int mt = 0; mt < 2; ++mt) {
    const int row = b * 512 + qc * 32 + mt * 16 + l15;
    qf[mt] = *(const bf16x8*)&qkv[(size_t)row * 768 + h * 32 + quad * 8];
  }
  const float scale = 0.17677669529663687f;  // 1/sqrt(32)
  for (int kt = w; kt < 32; kt += 4) {
    const int key = b * 512 + kt * 16 + l15;
    const bf16x8 kf = *(const bf16x8*)&qkv[(size_t)key * 768 + 256 + h * 32 + quad * 8];
#pragma unroll
    for (int mt = 0; mt < 2; ++mt) {
      f32x4 c = (f32x4){0.f, 0.f, 0.f, 0.f};
      c = __builtin_amdgcn_mfma_f32_16x16x32_bf16(qf[mt], kf, c, 0, 0, 0);
#pragma unroll
      for (int r = 0; r < 4; ++r)
        sP[(mt * 16 + quad * 4 + r) * 520 + kt * 16 + l15] = (bf16_t)(c[r] * scale);
    }
  }
  __syncthreads();

#pragma unroll
  for (int ri = 0; ri < 8; ++ri) {
    const int row = w * 8 + ri;
    const bf16x8 sv = *(const bf16x8*)&sP[row * 520 + lane * 8];
    float sval[8];
    float mx = -1e30f;
#pragma unroll
    for (int j = 0; j < 8; ++j) { sval[j] = (float)sv[j]; mx = fmaxf(mx, sval[j]); }
#pragma unroll
    for (int off = 32; off; off >>= 1) mx = fmaxf(mx, __shfl_xor(mx, off, 64));
    float sum = 0.f;
    bf16x8 pv;
#pragma unroll
    for (int j = 0; j < 8; ++j) { const float e = __expf(sval[j] - mx); sum += e; pv[j] = (bf16_t)e; }
#pragma unroll
    for (int off = 32; off; off >>= 1) sum += __shfl_xor(sum, off, 64);
    *(bf16x8*)&sP[row * 520 + lane * 8] = pv;
    if (lane == 0) sL[row] = sum;
  }
  __syncthreads();

  const int omt = w >> 1, ont = w & 1;
  f32x4 oacc = (f32x4){0.f, 0.f, 0.f, 0.f};
  for (int half = 0; half < 2; ++half) {
    if (half) __syncthreads();
#pragma unroll
    for (int i = 0; i < 32; ++i) {
      const int el = i * 256 + t;
      const int dh = el & 31, key = el >> 5;
      sVt[dh * 264 + key] = qkv[(size_t)(b * 512 + half * 256 + key) * 768 + 512 + h * 32 + dh];
    }
    __syncthreads();
#pragma unroll
    for (int kt = 0; kt < 8; ++kt) {
      const bf16x8 af = *(const bf16x8*)&sP[(omt * 16 + l15) * 520 + half * 256 + kt * 32 + quad * 8];
      const bf16x8 vf = *(const bf16x8*)&sVt[(ont * 16 + l15) * 264 + kt * 32 + quad * 8];
      oacc = __builtin_amdgcn_mfma_f32_16x16x32_bf16(af, vf, oacc, 0, 0, 0);
    }
  }
#pragma unroll
  for (int r = 0; r < 4; ++r) {
    const int row = omt * 16 + quad * 4 + r;
    const float val = oacc[r] / sL[row];
    obuf[(size_t)(b * 512 + qc * 32 + row) * 256 + h * 32 + ont * 16 + l15] = (bf16_t)val;
  }
}

// ---------------------------------------------------------------------------
__global__ __launch_bounds__(256)
void ln1_kernel(const float* __restrict__ S, const float* __restrict__ o2,
                const float* __restrict__ incom, const float* __restrict__ g,
                const float* __restrict__ bb, float* __restrict__ S1f,
                bf16_t* __restrict__ A4)
{
  const int w = threadIdx.x >> 6, lane = threadIdx.x & 63;
  const int row = blockIdx.x * 4 + w;
  const size_t base = (size_t)row * 256 + lane * 4;
  const float4 xs = *(const float4*)&S[base];
  const float4 xo = *(const float4*)&o2[base];
  float x[4] = {xs.x + xo.x, xs.y + xo.y, xs.z + xo.z, xs.w + xo.w};
  float sum = x[0] + x[1] + x[2] + x[3];
  float sq = x[0]*x[0] + x[1]*x[1] + x[2]*x[2] + x[3]*x[3];
#pragma unroll
  for (int off = 32; off; off >>= 1) { sum += __shfl_xor(sum, off, 64); sq += __shfl_xor(sq, off, 64); }
  const float mean = sum * 0.00390625f;
  const float var = sq * 0.00390625f - mean * mean;
  const float rstd = rsqrtf(var + LN_EPS);
  const float4 gg = *(const float4*)&g[lane * 4];
  const float4 bv = *(const float4*)&bb[lane * 4];
  float y[4];
  y[0] = (x[0]-mean)*rstd*gg.x + bv.x;
  y[1] = (x[1]-mean)*rstd*gg.y + bv.y;
  y[2] = (x[2]-mean)*rstd*gg.z + bv.z;
  y[3] = (x[3]-mean)*rstd*gg.w + bv.w;
  *(float4*)&S1f[base] = make_float4(y[0], y[1], y[2], y[3]);
  bf16x4v yb; yb[0]=(bf16_t)y[0]; yb[1]=(bf16_t)y[1]; yb[2]=(bf16_t)y[2]; yb[3]=(bf16_t)y[3];
  *(bf16x4v*)&A4[(size_t)row * 512 + lane * 4] = yb;
  const float4 ic = *(const float4*)&incom[base];
  bf16x4v ib; ib[0]=(bf16_t)ic.x; ib[1]=(bf16_t)ic.y; ib[2]=(bf16_t)ic.z; ib[3]=(bf16_t)ic.w;
  *(bf16x4v*)&A4[(size_t)row * 512 + 256 + lane * 4] = ib;
}

__global__ __launch_bounds__(256)
void ln2_kernel(const float* __restrict__ S2, const float* __restrict__ g,
                const float* __restrict__ bb, float* __restrict__ out)
{
  const int w = threadIdx.x >> 6, lane = threadIdx.x & 63;
  const int row = blockIdx.x * 4 + w;
  const size_t base = (size_t)row * 256 + lane * 4;
  const float4 xv = *(const float4*)&S2[base];
  float x[4] = {xv.x, xv.y, xv.z, xv.w};
  float sum = x[0] + x[1] + x[2] + x[3];
  float sq = x[0]*x[0] + x[1]*x[1] + x[2]*x[2] + x[3]*x[3];
#pragma unroll
  for (int off = 32; off; off >>= 1) { sum += __shfl_xor(sum, off, 64); sq += __shfl_xor(sq, off, 64); }
  const float mean = sum * 0.00390625f;
  const float var = sq * 0.00390625f - mean * mean;
  const float rstd = rsqrtf(var + LN_EPS);
  const float4 gg = *(const float4*)&g[lane * 4];
  const float4 bv = *(const float4*)&bb[lane * 4];
  float4 o;
  o.x = (x[0]-mean)*rstd*gg.x + bv.x;
  o.y = (x[1]-mean)*rstd*gg.y + bv.y;
  o.z = (x[2]-mean)*rstd*gg.z + bv.z;
  o.w = (x[3]-mean)*rstd*gg.w + bv.w;
  *(float4*)&out[base] = o;
}

// ---------------------------------------------------------------------------
extern "C" void kernel_launch(void* const* d_in, const int* in_sizes, int n_in,
                              void* d_out, int out_size, void* d_ws, size_t ws_size,
                              hipStream_t stream)
{
  (void)in_sizes; (void)n_in; (void)out_size; (void)ws_size;
  const float* X    = (const float*)d_in[0];
  const float* S    = (const float*)d_in[1];
  const float* Wg   = (const float*)d_in[2];
  const float* Wk   = (const float*)d_in[3];
  const float* Wm1  = (const float*)d_in[4];
  const float* bm1  = (const float*)d_in[5];
  const float* Wm2  = (const float*)d_in[6];
  const float* bm2  = (const float*)d_in[7];
  const float* Wgt1 = (const float*)d_in[8];
  const float* bgt1 = (const float*)d_in[9];
  const float* Wgt2 = (const float*)d_in[10];
  const float* bgt2 = (const float*)d_in[11];
  const float* Wqkv = (const float*)d_in[12];
  const float* bqkv = (const float*)d_in[13];
  const float* Wo   = (const float*)d_in[14];
  const float* bo   = (const float*)d_in[15];
  const float* alng = (const float*)d_in[16];
  const float* alnb = (const float*)d_in[17];
  const float* Wu1  = (const float*)d_in[18];
  const float* bu1  = (const float*)d_in[19];
  const float* Wu2  = (const float*)d_in[20];
  const float* bu2  = (const float*)d_in[21];
  const float* lng  = (const float*)d_in[22];
  const float* lnb  = (const float*)d_in[23];

  char* p = (char*)d_ws;
  auto carve = [&](size_t bytes) { char* r = p; p += bytes; return r; };
  bf16_t* Xb    = (bf16_t*)carve(16777216);   // 32768 x 256
  bf16_t* Sb    = (bf16_t*)carve(2097152);    // 4096 x 256
  bf16_t* W1t   = (bf16_t*)carve(458752);     // 896 x 256
  bf16_t* W2t   = (bf16_t*)carve(262144);     // 256 x 512
  bf16_t* Wqkvt = (bf16_t*)carve(393216);     // 768 x 256
  bf16_t* Wot   = (bf16_t*)carve(131072);     // 256 x 256
  bf16_t* Wu1t  = (bf16_t*)carve(524288);     // 512 x 512
  bf16_t* Wu2t  = (bf16_t*)carve(262144);     // 256 x 512
  bf16_t* h1g1  = (bf16_t*)carve(58720256);   // 32768 x 896
  int*    idxb  = (int*)carve(131072);
  float*  gateb = (float*)carve(131072);
  float*  incom = (float*)carve(4194304);     // 4096 x 256 f32
  bf16_t* qkvb  = (bf16_t*)carve(6291456);    // 4096 x 768
  bf16_t* obuf  = (bf16_t*)carve(2097152);    // 4096 x 256
  float*  o2    = (float*)carve(4194304);
  float*  S1f   = (float*)carve(4194304);
  bf16_t* A4    = (bf16_t*)carve(4194304);    // 4096 x 512
  bf16_t* U     = (bf16_t*)carve(4194304);    // 4096 x 512 (aliased by H)
  float*  S2    = (float*)carve(4194304);
  int*    counts  = (int*)carve(16384);       // 4096  (counts+cursor adjacent
  int*    cursor  = (int*)carve(16384);       //        -> one 32KB memset)
  int*    offsets = (int*)carve(16384);
  int*    perm    = (int*)carve(131072);      // 32768
  float*  sumg    = (float*)carve(16384);
  bf16_t* H = U;  // disjoint lifetime: H dead before U written

  prep_kernel<<<12160, 256, 0, stream>>>(X, S, Wg, Wk, Wm1, Wgt1, Wm2, Wqkv, Wo, Wu1, Wu2,
                                         Xb, Sb, W1t, W2t, Wqkvt, Wot, Wu1t, Wu2t);
  hipMemsetAsync(counts, 0, 32768, stream);
  // G1: X @ [Wm1|Wgt1|Wg|Wk]
  gemm_kernel<4,1><<<dim3(256,7), 256, 0, stream>>>(Xb, 256, W1t, 256, bm1, bgt1, h1g1, 896,
                                                    nullptr, nullptr);
  route_kernel<<<8192, 256, 0, stream>>>(h1g1, Wgt2, bgt2, idxb, gateb, counts);
  scan_kernel<<<1, 1024, 0, stream>>>(counts, offsets);
  fill_kernel<<<128, 256, 0, stream>>>(idxb, offsets, cursor, perm);
  gather_kernel<<<4096, 256, 0, stream>>>(h1g1, gateb, perm, offsets, counts, H, sumg);
  // incoming = H @ Wm2 + sumgate * bm2
  gemm_kernel<1,7><<<dim3(128,2), 256, 0, stream>>>(H, 512, W2t, 512, bm2, nullptr, incom, 256,
                                                    sumg, nullptr);
  // qkv
  gemm_kernel<1,3><<<dim3(128,6), 256, 0, stream>>>(Sb, 256, Wqkvt, 256, bqkv, nullptr, qkvb, 768,
                                                    nullptr, nullptr);
  attn_kernel<<<1024, 256, 0, stream>>>(qkvb, obuf);
  // o @ Wo
  gemm_kernel<1,4><<<dim3(128,2), 256, 0, stream>>>(obuf, 256, Wot, 256, bo, nullptr, o2, 256,
                                                    nullptr, nullptr);
  ln1_kernel<<<1024, 256, 0, stream>>>(S, o2, incom, alng, alnb, S1f, A4);
  // update MLP
  gemm_kernel<1,5><<<dim3(128,4), 256, 0, stream>>>(A4, 512, Wu1t, 512, bu1, nullptr, U, 512,
                                                    nullptr, nullptr);
  gemm_kernel<1,6><<<dim3(128,2), 256, 0, stream>>>(U, 512, Wu2t, 512, bu2, nullptr, S2, 256,
                                                    nullptr, S1f);
  ln2_kernel<<<1024, 256, 0, stream>>>(S2, lng, lnb, (float*)d_out);
}

// Round 5
// 271.822 us; speedup vs baseline: 1.4389x; 1.0663x over previous
//
#include <hip/hip_runtime.h>

typedef __bf16 bf16_t;
typedef __bf16 bf16x8 __attribute__((ext_vector_type(8)));
typedef __bf16 bf16x4v __attribute__((ext_vector_type(4)));
typedef __bf16 bf16x2v __attribute__((ext_vector_type(2)));
typedef float f32x4 __attribute__((ext_vector_type(4)));
typedef unsigned long long u64;

#define LN_EPS 1e-5f

// njuffa's 1-ulp erff (fast path for |a|<=0.921875 is 6 fma)
__device__ __forceinline__ float erf_fast(float a) {
  const float t = fabsf(a);
  const float s = a * a;
  float r;
  if (t > 0.921875f) {
    float u;
    r = fmaf(-1.72853470e-5f, t, 3.83197126e-4f);
    u = fmaf(-3.88396438e-3f, t, 2.42546219e-2f);
    r = fmaf(r, s, u);
    r = fmaf(r, t, 1.06777877e-1f);
    r = fmaf(r, t, -6.37245935e-1f);
    r = fmaf(r, t, -1.28717512e-1f);
    r = fmaf(r, t, t);
    r = 1.0f - __expf(-r);
    r = copysignf(r, a);
  } else {
    r = -5.96761703e-4f;
    r = fmaf(r, s, 4.99119423e-3f);
    r = fmaf(r, s, -2.67681349e-2f);
    r = fmaf(r, s, 1.12819925e-1f);
    r = fmaf(r, s, -3.76125336e-1f);
    r = fmaf(r, s, 1.28379166e-1f);
    r = fmaf(r, a, a);
  }
  return r;
}

__device__ __forceinline__ float gelu_f(float x) {
  const float h = 0.5f * x;
  return fmaf(h, erf_fast(x * 0.70710678118654752f), h);
}

__device__ __forceinline__ void async16(const bf16_t* g, bf16_t* l) {
  __builtin_amdgcn_global_load_lds(
      (const __attribute__((address_space(1))) void*)g,
      (__attribute__((address_space(3))) void*)l, 16, 0, 0);
}

// ---------------------------------------------------------------------------
// prep: X,S -> bf16 ; weights -> transposed bf16 ; zero bitmap+gatelin
// ---------------------------------------------------------------------------
__global__ __launch_bounds__(256)
void prep_kernel(const float* __restrict__ X, const float* __restrict__ S,
                 const float* __restrict__ Wg, const float* __restrict__ Wk,
                 const float* __restrict__ Wm1, const float* __restrict__ Wgt1,
                 const float* __restrict__ Wm2, const float* __restrict__ Wqkv,
                 const float* __restrict__ Wo, const float* __restrict__ Wu1,
                 const float* __restrict__ Wu2,
                 bf16_t* __restrict__ Xb, bf16_t* __restrict__ Sb,
                 bf16_t* __restrict__ W1t, bf16_t* __restrict__ W2t,
                 bf16_t* __restrict__ Wqkvt, bf16_t* __restrict__ Wot,
                 bf16_t* __restrict__ Wu1t, bf16_t* __restrict__ Wu2t,
                 float4* __restrict__ zbase)
{
  const int bid = blockIdx.x;
  const int t = threadIdx.x;
  if (bid < 8192) {                       // X
    const int i = bid * 256 + t;
    const float4 v = ((const float4*)X)[i];
    bf16x4v o; o[0]=(bf16_t)v.x; o[1]=(bf16_t)v.y; o[2]=(bf16_t)v.z; o[3]=(bf16_t)v.w;
    ((bf16x4v*)Xb)[i] = o;
  } else if (bid < 9216) {                // S
    const int i = (bid - 8192) * 256 + t;
    const float4 v = ((const float4*)S)[i];
    bf16x4v o; o[0]=(bf16_t)v.x; o[1]=(bf16_t)v.y; o[2]=(bf16_t)v.z; o[3]=(bf16_t)v.w;
    ((bf16x4v*)Sb)[i] = o;
  } else if (bid < 10112) {               // W1t: 896 rows x 256
    const int n = bid - 9216;
    const int k = t;
    float v;
    if (n < 512)      v = Wm1[k * 512 + n];
    else if (n < 768) v = Wgt1[k * 256 + (n - 512)];
    else if (n < 832) v = Wg[k * 64 + (n - 768)];
    else if (n < 840) v = Wk[k * 8 + (n - 832)];
    else              v = 0.f;
    W1t[n * 256 + k] = (bf16_t)v;
  } else if (bid < 10368) {               // W2t: 256 rows x 512
    const int n = bid - 10112;
    for (int k = t; k < 512; k += 256) W2t[n * 512 + k] = (bf16_t)Wm2[k * 256 + n];
  } else if (bid < 11136) {               // Wqkvt: 768 x 256
    const int n = bid - 10368;
    Wqkvt[n * 256 + t] = (bf16_t)Wqkv[t * 768 + n];
  } else if (bid < 11392) {               // Wot: 256 x 256
    const int n = bid - 11136;
    Wot[n * 256 + t] = (bf16_t)Wo[t * 256 + n];
  } else if (bid < 11904) {               // Wu1t: 512 x 512
    const int n = bid - 11392;
    for (int k = t; k < 512; k += 256) Wu1t[n * 512 + k] = (bf16_t)Wu1[k * 512 + n];
  } else if (bid < 12160) {               // Wu2t: 256 x 512
    const int n = bid - 11904;
    for (int k = t; k < 512; k += 256) Wu2t[n * 512 + k] = (bf16_t)Wu2[k * 256 + n];
  } else {                                // zero bitmap (2MB) + gatelin (128KB)
    zbase[(bid - 12160) * 256 + t] = make_float4(0.f, 0.f, 0.f, 0.f);
  }
}

// ---------------------------------------------------------------------------
// bf16 MFMA GEMM: C[M x N] = A[M x K] * Bt[N x K]^T, tile (MT*32) x 128, BK=32
// MFMA operands swapped: lane's 4 acc regs = 4 consecutive cols of one row.
// EPI 1 (G1R): by<4 -> gelu(+bm1) -> h1 (ldc=512)
//              by 4/5 -> gelu(+bgt1), dot with Wgt2 -> atomicAdd gatelin
//              by 6 -> argmax(Wg),argmax(Wk) -> idxb + bitmap atomicOr
// EPI 4: +bias -> f32     EPI 5: gelu(+bias) -> bf16     EPI 6: +bias+resid -> f32
// ---------------------------------------------------------------------------
template<int MT, int EPI>
__global__ __launch_bounds__(256)
void gemm_kernel(const bf16_t* __restrict__ A, int lda,
                 const bf16_t* __restrict__ Bt, int K,
                 const float* __restrict__ bias, const float* __restrict__ bias2,
                 void* __restrict__ outp, int ldc,
                 const float* __restrict__ resid, const float* __restrict__ wgt2,
                 float* __restrict__ gatelin, int* __restrict__ idxb,
                 u64* __restrict__ bitmap)
{
  constexpr int BM = MT * 32;
  constexpr int CA = BM * 4;             // 16B chunks per k-pass (A)
  const int m0 = blockIdx.x * BM;
  const int by = blockIdx.y;
  const int n0 = by * 128;
  const int t = threadIdx.x;
  const int w = t >> 6;
  const int lane = t & 63;
  const int wr = w >> 1, wc = w & 1;
  const int quad = lane >> 4, l15 = lane & 15;

  __shared__ bf16_t lA[BM * 32];
  __shared__ bf16_t lB[128 * 32];
  __shared__ float sWg[256];
  __shared__ int sKi[128];

  if constexpr (EPI == 1) {
    if (by >= 4 && by < 6) sWg[t] = wgt2[t];
  }

  f32x4 acc[MT][4];
#pragma unroll
  for (int mt = 0; mt < MT; ++mt)
#pragma unroll
    for (int nt = 0; nt < 4; ++nt)
      acc[mt][nt] = (f32x4){0.f, 0.f, 0.f, 0.f};

  for (int k0 = 0; k0 < K; k0 += 32) {
    if constexpr (CA >= 256) {
#pragma unroll
      for (int i = 0; i < CA / 256; ++i) {
        const int c = i * 256 + t;
        async16(A + (size_t)(m0 + (c >> 2)) * lda + k0 + (c & 3) * 8,
                lA + (size_t)(i * 256 + (t & 192)) * 8);
      }
    } else {
      if (t < CA)
        async16(A + (size_t)(m0 + (t >> 2)) * lda + k0 + (t & 3) * 8,
                lA + (size_t)(t & 192) * 8);
    }
#pragma unroll
    for (int i = 0; i < 2; ++i) {
      const int c = i * 256 + t;
      async16(Bt + (size_t)(n0 + (c >> 2)) * K + k0 + (c & 3) * 8,
              lB + (size_t)(i * 256 + (t & 192)) * 8);
    }
    __syncthreads();
    bf16x8 af[MT], bfr[4];
    const int ko = quad * 8;
#pragma unroll
    for (int mt = 0; mt < MT; ++mt)
      af[mt] = *(const bf16x8*)&lA[(wr * MT * 16 + mt * 16 + l15) * 32 + ko];
#pragma unroll
    for (int nt = 0; nt < 4; ++nt)
      bfr[nt] = *(const bf16x8*)&lB[(wc * 64 + nt * 16 + l15) * 32 + ko];
#pragma unroll
    for (int mt = 0; mt < MT; ++mt)
#pragma unroll
      for (int nt = 0; nt < 4; ++nt)
        acc[mt][nt] = __builtin_amdgcn_mfma_f32_16x16x32_bf16(bfr[nt], af[mt], acc[mt][nt], 0, 0, 0);
    __syncthreads();
  }

  if constexpr (EPI == 1) {
    if (by < 4) {
      // msg: gelu(v + bm1) -> h1 bf16, ldc = 512
#pragma unroll
      for (int mt = 0; mt < MT; ++mt) {
        const int row = m0 + wr * MT * 16 + mt * 16 + l15;
#pragma unroll
        for (int nt = 0; nt < 4; ++nt) {
          const int colb = n0 + wc * 64 + nt * 16 + quad * 4;
          const float4 bb = *(const float4*)&bias[colb];
          bf16x4v o;
          o[0] = (bf16_t)gelu_f(acc[mt][nt][0] + bb.x);
          o[1] = (bf16_t)gelu_f(acc[mt][nt][1] + bb.y);
          o[2] = (bf16_t)gelu_f(acc[mt][nt][2] + bb.z);
          o[3] = (bf16_t)gelu_f(acc[mt][nt][3] + bb.w);
          *(bf16x4v*)&((bf16_t*)outp)[(size_t)row * 512 + colb] = o;
        }
      }
    } else if (by < 6) {
      // gate strips: partial dot of gelu(g1) with Wgt2 -> atomicAdd gatelin
#pragma unroll
      for (int mt = 0; mt < MT; ++mt) {
        const int row = m0 + wr * MT * 16 + mt * 16 + l15;
        float part = 0.f;
#pragma unroll
        for (int nt = 0; nt < 4; ++nt) {
          const int colb = n0 + wc * 64 + nt * 16 + quad * 4;
          const int c = colb - 512;
          const float4 bb = *(const float4*)&bias2[c];
          part = fmaf(gelu_f(acc[mt][nt][0] + bb.x), sWg[c + 0], part);
          part = fmaf(gelu_f(acc[mt][nt][1] + bb.y), sWg[c + 1], part);
          part = fmaf(gelu_f(acc[mt][nt][2] + bb.z), sWg[c + 2], part);
          part = fmaf(gelu_f(acc[mt][nt][3] + bb.w), sWg[c + 3], part);
        }
        part += __shfl_xor(part, 16, 64);
        part += __shfl_xor(part, 32, 64);
        if (lane < 16) atomicAdd(&gatelin[row], part);
      }
    } else {
      // logit strip: argmax(g)*8 + argmax(k) -> idxb, bitmap
      float bv[MT]; int bi[MT];
#pragma unroll
      for (int mt = 0; mt < MT; ++mt) {
        if (wc == 0) {
          // group logits: local cols 0..63
          float mv = -1e30f; int mi = 0;
#pragma unroll
          for (int nt = 0; nt < 4; ++nt)
#pragma unroll
            for (int j = 0; j < 4; ++j) {
              const int gc = nt * 16 + quad * 4 + j;
              const float v = acc[mt][nt][j];
              if (v > mv || (v == mv && gc < mi)) { mv = v; mi = gc; }
            }
#pragma unroll
          for (int off = 16; off <= 32; off <<= 1) {
            const float ov = __shfl_xor(mv, off, 64);
            const int oi = __shfl_xor(mi, off, 64);
            if (ov > mv || (ov == mv && oi < mi)) { mv = ov; mi = oi; }
          }
          bv[mt] = mv; bi[mt] = mi;
        } else {
          // k logits: local cols 64..71 -> nt=0, quad<2
          float mv = -1e30f; int mi = 0;
          if (quad < 2) {
#pragma unroll
            for (int j = 0; j < 4; ++j) {
              const int kc = quad * 4 + j;
              const float v = acc[mt][0][j];
              if (v > mv || (v == mv && kc < mi)) { mv = v; mi = kc; }
            }
          }
#pragma unroll
          for (int off = 16; off <= 32; off <<= 1) {
            const float ov = __shfl_xor(mv, off, 64);
            const int oi = __shfl_xor(mi, off, 64);
            if (ov > mv || (ov == mv && oi < mi)) { mv = ov; mi = oi; }
          }
          if (lane < 16) sKi[wr * MT * 16 + mt * 16 + l15] = mi;
        }
      }
      __syncthreads();
      if (wc == 0 && lane < 16) {
#pragma unroll
        for (int mt = 0; mt < MT; ++mt) {
          const int rl = wr * MT * 16 + mt * 16 + l15;
          const int row = m0 + rl;
          const int idx = bi[mt] * 8 + sKi[rl];
          idxb[row] = idx;
          const int b = row >> 12, tok = row & 4095;
          atomicOr(&bitmap[(size_t)(b * 512 + idx) * 64 + (tok >> 6)],
                   1ull << (tok & 63));
        }
      }
    }
  } else {
#pragma unroll
    for (int mt = 0; mt < MT; ++mt) {
      const int row = m0 + wr * MT * 16 + mt * 16 + l15;
#pragma unroll
      for (int nt = 0; nt < 4; ++nt) {
        const int colb = n0 + wc * 64 + nt * 16 + quad * 4;
        const float4 bb = *(const float4*)&bias[colb];
        float v0 = acc[mt][nt][0] + bb.x, v1 = acc[mt][nt][1] + bb.y;
        float v2 = acc[mt][nt][2] + bb.z, v3 = acc[mt][nt][3] + bb.w;
        if constexpr (EPI == 4) {
          *(float4*)&((float*)outp)[(size_t)row * ldc + colb] = make_float4(v0, v1, v2, v3);
        } else if constexpr (EPI == 5) {
          bf16x4v o; o[0]=(bf16_t)gelu_f(v0); o[1]=(bf16_t)gelu_f(v1);
          o[2]=(bf16_t)gelu_f(v2); o[3]=(bf16_t)gelu_f(v3);
          *(bf16x4v*)&((bf16_t*)outp)[(size_t)row * ldc + colb] = o;
        } else {  // EPI 6
          const float4 rr = *(const float4*)&resid[(size_t)row * ldc + colb];
          *(float4*)&((float*)outp)[(size_t)row * ldc + colb] =
              make_float4(v0 + rr.x, v1 + rr.y, v2 + rr.z, v3 + rr.w);
        }
      }
    }
  }
}

// ---------------------------------------------------------------------------
// pair: blocks [0,256) = G2' (incoming = H@Wm2 + sumg*bm2, f32)
//       blocks [256,1024) = qkv (Sb@Wqkvt + bqkv, bf16)
// ---------------------------------------------------------------------------
__global__ __launch_bounds__(256)
void gemm_pair_kernel(const bf16_t* __restrict__ H, const bf16_t* __restrict__ W2t,
                      const float* __restrict__ bm2, const float* __restrict__ sumg,
                      float* __restrict__ incom,
                      const bf16_t* __restrict__ Sb, const bf16_t* __restrict__ Wqkvt,
                      const float* __restrict__ bqkv, bf16_t* __restrict__ qkvb)
{
  int id = blockIdx.x;
  const bool first = id < 256;
  if (!first) id -= 256;
  const bf16_t* A  = first ? H : Sb;
  const bf16_t* Bt = first ? W2t : Wqkvt;
  const float* bias = first ? bm2 : bqkv;
  const int lda = first ? 512 : 256;
  const int K   = first ? 512 : 256;
  const int ldc = first ? 256 : 768;
  const int m0 = (id & 127) * 32;
  const int n0 = (id >> 7) * 128;
  const int t = threadIdx.x;
  const int w = t >> 6;
  const int lane = t & 63;
  const int wr = w >> 1, wc = w & 1;
  const int quad = lane >> 4, l15 = lane & 15;

  __shared__ bf16_t lA[32 * 32];
  __shared__ bf16_t lB[128 * 32];

  f32x4 acc[4];
#pragma unroll
  for (int nt = 0; nt < 4; ++nt) acc[nt] = (f32x4){0.f, 0.f, 0.f, 0.f};

  for (int k0 = 0; k0 < K; k0 += 32) {
    if (t < 128)
      async16(A + (size_t)(m0 + (t >> 2)) * lda + k0 + (t & 3) * 8,
              lA + (size_t)(t & 192) * 8);
#pragma unroll
    for (int i = 0; i < 2; ++i) {
      const int c = i * 256 + t;
      async16(Bt + (size_t)(n0 + (c >> 2)) * K + k0 + (c & 3) * 8,
              lB + (size_t)(i * 256 + (t & 192)) * 8);
    }
    __syncthreads();
    bf16x8 af, bfr[4];
    const int ko = quad * 8;
    af = *(const bf16x8*)&lA[(wr * 16 + l15) * 32 + ko];
#pragma unroll
    for (int nt = 0; nt < 4; ++nt)
      bfr[nt] = *(const bf16x8*)&lB[(wc * 64 + nt * 16 + l15) * 32 + ko];
#pragma unroll
    for (int nt = 0; nt < 4; ++nt)
      acc[nt] = __builtin_amdgcn_mfma_f32_16x16x32_bf16(bfr[nt], af, acc[nt], 0, 0, 0);
    __syncthreads();
  }

  const int row = m0 + wr * 16 + l15;
  if (first) {
    const float gt = sumg[row];
#pragma unroll
    for (int nt = 0; nt < 4; ++nt) {
      const int colb = n0 + wc * 64 + nt * 16 + quad * 4;
      const float4 bb = *(const float4*)&bias[colb];
      *(float4*)&incom[(size_t)row * ldc + colb] =
          make_float4(fmaf(gt, bb.x, acc[nt][0]), fmaf(gt, bb.y, acc[nt][1]),
                      fmaf(gt, bb.z, acc[nt][2]), fmaf(gt, bb.w, acc[nt][3]));
    }
  } else {
#pragma unroll
    for (int nt = 0; nt < 4; ++nt) {
      const int colb = n0 + wc * 64 + nt * 16 + quad * 4;
      const float4 bb = *(const float4*)&bias[colb];
      bf16x4v o; o[0]=(bf16_t)(acc[nt][0]+bb.x); o[1]=(bf16_t)(acc[nt][1]+bb.y);
      o[2]=(bf16_t)(acc[nt][2]+bb.z); o[3]=(bf16_t)(acc[nt][3]+bb.w);
      *(bf16x4v*)&qkvb[(size_t)row * ldc + colb] = o;
    }
  }
}

// ---------------------------------------------------------------------------
// gather: block per (b,slot); bitmap-driven; H = sum gate*h1 rows; sumg
// ---------------------------------------------------------------------------
__global__ __launch_bounds__(256)
void gather_kernel(const bf16_t* __restrict__ h1, const float* __restrict__ gatelin,
                   const float* __restrict__ bgt2, const u64* __restrict__ bitmap,
                   bf16_t* __restrict__ H, float* __restrict__ sumg)
{
  const int bs = blockIdx.x;
  const int b = bs >> 9;
  const int t = threadIdx.x;
  __shared__ u64 sw[64];
  if (t < 64) sw[t] = bitmap[(size_t)bs * 64 + t];
  __syncthreads();
  const float bg = bgt2[0];
  float a0 = 0.f, a1 = 0.f, sg = 0.f;
  for (int wd = 0; wd < 64; ++wd) {
    u64 word = sw[wd];
    while (word) {
      const int bit = __builtin_ctzll(word);
      word &= word - 1;
      const int l = (b << 12) + (wd << 6) + bit;
      const float g = 1.0f / (1.0f + __expf(-(gatelin[l] + bg)));
      const bf16x2v hv = *(const bf16x2v*)&h1[(size_t)l * 512 + t * 2];
      a0 = fmaf(g, (float)hv[0], a0);
      a1 = fmaf(g, (float)hv[1], a1);
      sg += g;
    }
  }
  bf16x2v o; o[0] = (bf16_t)a0; o[1] = (bf16_t)a1;
  *(bf16x2v*)&H[(size_t)bs * 512 + t * 2] = o;
  if (t == 0) sumg[bs] = sg;
}

// ---------------------------------------------------------------------------
// fused slot attention: block = (b, h, 32-query chunk)
// ---------------------------------------------------------------------------
__global__ __launch_bounds__(256)
void attn_kernel(const bf16_t* __restrict__ qkv, bf16_t* __restrict__ obuf)
{
  const int bid = blockIdx.x;
  const int qc = bid & 15;
  const int h = (bid >> 4) & 7;
  const int b = bid >> 7;
  const int t = threadIdx.x;
  const int w = t >> 6, lane = t & 63;
  const int quad = lane >> 4, l15 = lane & 15;

  __shared__ bf16_t sP[32 * 520];
  __shared__ bf16_t sVt[32 * 264];
  __shared__ float sL[32];

  bf16x8 qf[2];
#pragma unroll
  for (int mt = 0; mt < 2; ++mt) {
    const int row = b * 512 + qc * 32 + mt * 16 + l15;
    qf[mt] = *(const bf16x8*)&qkv[(size_t)row * 768 + h * 32 + quad * 8];
  }
  const float scale = 0.17677669529663687f;  // 1/sqrt(32)
  for (int kt = w; kt < 32; kt += 4) {
    const int key = b * 512 + kt * 16 + l15;
    const bf16x8 kf = *(const bf16x8*)&qkv[(size_t)key * 768 + 256 + h * 32 + quad * 8];
#pragma unroll
    for (int mt = 0; mt < 2; ++mt) {
      f32x4 c = (f32x4){0.f, 0.f, 0.f, 0.f};
      c = __builtin_amdgcn_mfma_f32_16x16x32_bf16(qf[mt], kf, c, 0, 0, 0);
#pragma unroll
      for (int r = 0; r < 4; ++r)
        sP[(mt * 16 + quad * 4 + r) * 520 + kt * 16 + l15] = (bf16_t)(c[r] * scale);
    }
  }
  __syncthreads();

#pragma unroll
  for (int ri = 0; ri < 8; ++ri) {
    const int row = w * 8 + ri;
    const bf16x8 sv = *(const bf16x8*)&sP[row * 520 + lane * 8];
    float sval[8];
    float mx = -1e30f;
#pragma unroll
    for (int j = 0; j < 8; ++j) { sval[j] = (float)sv[j]; mx = fmaxf(mx, sval[j]); }
#pragma unroll
    for (int off = 32; off; off >>= 1) mx = fmaxf(mx, __shfl_xor(mx, off, 64));
    float sum = 0.f;
    bf16x8 pv;
#pragma unroll
    for (int j = 0; j < 8; ++j) { const float e = __expf(sval[j] - mx); sum += e; pv[j] = (bf16_t)e; }
#pragma unroll
    for (int off = 32; off; off >>= 1) sum += __shfl_xor(sum, off, 64);
    *(bf16x8*)&sP[row * 520 + lane * 8] = pv;
    if (lane == 0) sL[row] = sum;
  }
  __syncthreads();

  const int omt = w >> 1, ont = w & 1;
  f32x4 oacc = (f32x4){0.f, 0.f, 0.f, 0.f};
  for (int half = 0; half < 2; ++half) {
    if (half) __syncthreads();
#pragma unroll
    for (int i = 0; i < 32; ++i) {
      const int el = i * 256 + t;
      const int dh = el & 31, key = el >> 5;
      sVt[dh * 264 + key] = qkv[(size_t)(b * 512 + half * 256 + key) * 768 + 512 + h * 32 + dh];
    }
    __syncthreads();
#pragma unroll
    for (int kt = 0; kt < 8; ++kt) {
      const bf16x8 af = *(const bf16x8*)&sP[(omt * 16 + l15) * 520 + half * 256 + kt * 32 + quad * 8];
      const bf16x8 vf = *(const bf16x8*)&sVt[(ont * 16 + l15) * 264 + kt * 32 + quad * 8];
      oacc = __builtin_amdgcn_mfma_f32_16x16x32_bf16(af, vf, oacc, 0, 0, 0);
    }
  }
#pragma unroll
  for (int r = 0; r < 4; ++r) {
    const int row = omt * 16 + quad * 4 + r;
    const float val = oacc[r] / sL[row];
    obuf[(size_t)(b * 512 + qc * 32 + row) * 256 + h * 32 + ont * 16 + l15] = (bf16_t)val;
  }
}

// ---------------------------------------------------------------------------
__global__ __launch_bounds__(256)
void ln1_kernel(const float* __restrict__ S, const float* __restrict__ o2,
                const float* __restrict__ incom, const float* __restrict__ g,
                const float* __restrict__ bb, float* __restrict__ S1f,
                bf16_t* __restrict__ A4)
{
  const int w = threadIdx.x >> 6, lane = threadIdx.x & 63;
  const int row = blockIdx.x * 4 + w;
  const size_t base = (size_t)row * 256 + lane * 4;
  const float4 xs = *(const float4*)&S[base];
  const float4 xo = *(const float4*)&o2[base];
  float x[4] = {xs.x + xo.x, xs.y + xo.y, xs.z + xo.z, xs.w + xo.w};
  float sum = x[0] + x[1] + x[2] + x[3];
  float sq = x[0]*x[0] + x[1]*x[1] + x[2]*x[2] + x[3]*x[3];
#pragma unroll
  for (int off = 32; off; off >>= 1) { sum += __shfl_xor(sum, off, 64); sq += __shfl_xor(sq, off, 64); }
  const float mean = sum * 0.00390625f;
  const float var = sq * 0.00390625f - mean * mean;
  const float rstd = rsqrtf(var + LN_EPS);
  const float4 gg = *(const float4*)&g[lane * 4];
  const float4 bv = *(const float4*)&bb[lane * 4];
  float y[4];
  y[0] = (x[0]-mean)*rstd*gg.x + bv.x;
  y[1] = (x[1]-mean)*rstd*gg.y + bv.y;
  y[2] = (x[2]-mean)*rstd*gg.z + bv.z;
  y[3] = (x[3]-mean)*rstd*gg.w + bv.w;
  *(float4*)&S1f[base] = make_float4(y[0], y[1], y[2], y[3]);
  bf16x4v yb; yb[0]=(bf16_t)y[0]; yb[1]=(bf16_t)y[1]; yb[2]=(bf16_t)y[2]; yb[3]=(bf16_t)y[3];
  *(bf16x4v*)&A4[(size_t)row * 512 + lane * 4] = yb;
  const float4 ic = *(const float4*)&incom[base];
  bf16x4v ib; ib[0]=(bf16_t)ic.x; ib[1]=(bf16_t)ic.y; ib[2]=(bf16_t)ic.z; ib[3]=(bf16_t)ic.w;
  *(bf16x4v*)&A4[(size_t)row * 512 + 256 + lane * 4] = ib;
}

__global__ __launch_bounds__(256)
void ln2_kernel(const float* __restrict__ S2, const float* __restrict__ g,
                const float* __restrict__ bb, float* __restrict__ out)
{
  const int w = threadIdx.x >> 6, lane = threadIdx.x & 63;
  const int row = blockIdx.x * 4 + w;
  const size_t base = (size_t)row * 256 + lane * 4;
  const float4 xv = *(const float4*)&S2[base];
  float x[4] = {xv.x, xv.y, xv.z, xv.w};
  float sum = x[0] + x[1] + x[2] + x[3];
  float sq = x[0]*x[0] + x[1]*x[1] + x[2]*x[2] + x[3]*x[3];
#pragma unroll
  for (int off = 32; off; off >>= 1) { sum += __shfl_xor(sum, off, 64); sq += __shfl_xor(sq, off, 64); }
  const float mean = sum * 0.00390625f;
  const float var = sq * 0.00390625f - mean * mean;
  const float rstd = rsqrtf(var + LN_EPS);
  const float4 gg = *(const float4*)&g[lane * 4];
  const float4 bv = *(const float4*)&bb[lane * 4];
  float4 o;
  o.x = (x[0]-mean)*rstd*gg.x + bv.x;
  o.y = (x[1]-mean)*rstd*gg.y + bv.y;
  o.z = (x[2]-mean)*rstd*gg.z + bv.z;
  o.w = (x[3]-mean)*rstd*gg.w + bv.w;
  *(float4*)&out[base] = o;
}

// ---------------------------------------------------------------------------
extern "C" void kernel_launch(void* const* d_in, const int* in_sizes, int n_in,
                              void* d_out, int out_size, void* d_ws, size_t ws_size,
                              hipStream_t stream)
{
  (void)in_sizes; (void)n_in; (void)out_size; (void)ws_size;
  const float* X    = (const float*)d_in[0];
  const float* S    = (const float*)d_in[1];
  const float* Wg   = (const float*)d_in[2];
  const float* Wk   = (const float*)d_in[3];
  const float* Wm1  = (const float*)d_in[4];
  const float* bm1  = (const float*)d_in[5];
  const float* Wm2  = (const float*)d_in[6];
  const float* bm2  = (const float*)d_in[7];
  const float* Wgt1 = (const float*)d_in[8];
  const float* bgt1 = (const float*)d_in[9];
  const float* Wgt2 = (const float*)d_in[10];
  const float* bgt2 = (const float*)d_in[11];
  const float* Wqkv = (const float*)d_in[12];
  const float* bqkv = (const float*)d_in[13];
  const float* Wo   = (const float*)d_in[14];
  const float* bo   = (const float*)d_in[15];
  const float* alng = (const float*)d_in[16];
  const float* alnb = (const float*)d_in[17];
  const float* Wu1  = (const float*)d_in[18];
  const float* bu1  = (const float*)d_in[19];
  const float* Wu2  = (const float*)d_in[20];
  const float* bu2  = (const float*)d_in[21];
  const float* lng  = (const float*)d_in[22];
  const float* lnb  = (const float*)d_in[23];

  char* p = (char*)d_ws;
  auto carve = [&](size_t bytes) { char* r = p; p += bytes; return r; };
  bf16_t* Xb    = (bf16_t*)carve(16777216);   // 32768 x 256
  bf16_t* Sb    = (bf16_t*)carve(2097152);    // 4096 x 256
  bf16_t* W1t   = (bf16_t*)carve(458752);     // 896 x 256
  bf16_t* W2t   = (bf16_t*)carve(262144);     // 256 x 512
  bf16_t* Wqkvt = (bf16_t*)carve(393216);     // 768 x 256
  bf16_t* Wot   = (bf16_t*)carve(131072);     // 256 x 256
  bf16_t* Wu1t  = (bf16_t*)carve(524288);     // 512 x 512
  bf16_t* Wu2t  = (bf16_t*)carve(262144);     // 256 x 512
  bf16_t* h1    = (bf16_t*)carve(33554432);   // 32768 x 512 (msg only)
  u64*    bitmap  = (u64*)carve(2097152);     // 4096 slots x 64 words (zeroed by prep)
  float*  gatelin = (float*)carve(131072);    // 32768 (zeroed by prep, adjacent)
  int*    idxb  = (int*)carve(131072);
  float*  incom = (float*)carve(4194304);     // 4096 x 256 f32
  bf16_t* qkvb  = (bf16_t*)carve(6291456);    // 4096 x 768
  bf16_t* obuf  = (bf16_t*)carve(2097152);    // 4096 x 256
  float*  o2    = (float*)carve(4194304);
  float*  S1f   = (float*)carve(4194304);
  bf16_t* A4    = (bf16_t*)carve(4194304);    // 4096 x 512
  bf16_t* U     = (bf16_t*)carve(4194304);    // 4096 x 512 (aliased by H)
  float*  S2    = (float*)carve(4194304);
  float*  sumg  = (float*)carve(16384);
  bf16_t* H = U;  // disjoint lifetime: H dead before U written

  // 1. prep (+ zero bitmap & gatelin: 2228224 B = 544 blocks x 4 KB)
  prep_kernel<<<12704, 256, 0, stream>>>(X, S, Wg, Wk, Wm1, Wgt1, Wm2, Wqkv, Wo, Wu1, Wu2,
                                         Xb, Sb, W1t, W2t, Wqkvt, Wot, Wu1t, Wu2t,
                                         (float4*)bitmap);
  // 2. G1 + fused routing
  gemm_kernel<4,1><<<dim3(256,7), 256, 0, stream>>>(Xb, 256, W1t, 256, bm1, bgt1, h1, 512,
                                                    nullptr, Wgt2, gatelin, idxb, bitmap);
  // 3. bitmap-driven aggregate
  gather_kernel<<<4096, 256, 0, stream>>>(h1, gatelin, bgt2, bitmap, H, sumg);
  // 4. G2' (incoming) + qkv in one dispatch
  gemm_pair_kernel<<<1024, 256, 0, stream>>>(H, W2t, bm2, sumg, incom,
                                             Sb, Wqkvt, bqkv, qkvb);
  // 5. attention
  attn_kernel<<<1024, 256, 0, stream>>>(qkvb, obuf);
  // 6. o @ Wo
  gemm_kernel<1,4><<<dim3(128,2), 256, 0, stream>>>(obuf, 256, Wot, 256, bo, nullptr, o2, 256,
                                                    nullptr, nullptr, nullptr, nullptr, nullptr);
  // 7. LN1 + pack
  ln1_kernel<<<1024, 256, 0, stream>>>(S, o2, incom, alng, alnb, S1f, A4);
  // 8. update MLP hidden
  gemm_kernel<1,5><<<dim3(128,4), 256, 0, stream>>>(A4, 512, Wu1t, 512, bu1, nullptr, U, 512,
                                                    nullptr, nullptr, nullptr, nullptr, nullptr);
  // 9. update MLP out + residual
  gemm_kernel<1,6><<<dim3(128,2), 256, 0, stream>>>(U, 512, Wu2t, 512, bu2, nullptr, S2, 256,
                                                    S1f, nullptr, nullptr, nullptr, nullptr);
  // 10. LN2 -> out
  ln2_kernel<<<1024, 256, 0, stream>>>(S2, lng, lnb, (float*)d_out);
}

// Round 6
// 260.921 us; speedup vs baseline: 1.4990x; 1.0418x over previous
//
#include <hip/hip_runtime.h>

typedef __bf16 bf16_t;
typedef __bf16 bf16x8 __attribute__((ext_vector_type(8)));
typedef __bf16 bf16x4v __attribute__((ext_vector_type(4)));
typedef __bf16 bf16x2v __attribute__((ext_vector_type(2)));
typedef float f32x4 __attribute__((ext_vector_type(4)));
typedef unsigned long long u64;

#define LN_EPS 1e-5f

// njuffa's 1-ulp erff (fast path for |a|<=0.921875 is 6 fma)
__device__ __forceinline__ float erf_fast(float a) {
  const float t = fabsf(a);
  const float s = a * a;
  float r;
  if (t > 0.921875f) {
    float u;
    r = fmaf(-1.72853470e-5f, t, 3.83197126e-4f);
    u = fmaf(-3.88396438e-3f, t, 2.42546219e-2f);
    r = fmaf(r, s, u);
    r = fmaf(r, t, 1.06777877e-1f);
    r = fmaf(r, t, -6.37245935e-1f);
    r = fmaf(r, t, -1.28717512e-1f);
    r = fmaf(r, t, t);
    r = 1.0f - __expf(-r);
    r = copysignf(r, a);
  } else {
    r = -5.96761703e-4f;
    r = fmaf(r, s, 4.99119423e-3f);
    r = fmaf(r, s, -2.67681349e-2f);
    r = fmaf(r, s, 1.12819925e-1f);
    r = fmaf(r, s, -3.76125336e-1f);
    r = fmaf(r, s, 1.28379166e-1f);
    r = fmaf(r, a, a);
  }
  return r;
}

__device__ __forceinline__ float gelu_f(float x) {
  const float h = 0.5f * x;
  return fmaf(h, erf_fast(x * 0.70710678118654752f), h);
}

__device__ __forceinline__ void async16(const bf16_t* g, bf16_t* l) {
  __builtin_amdgcn_global_load_lds(
      (const __attribute__((address_space(1))) void*)g,
      (__attribute__((address_space(3))) void*)l, 16, 0, 0);
}

// ---------------------------------------------------------------------------
// prep: X,S -> bf16 ; weights -> transposed bf16 ; zero bitmap+gatelin
// ---------------------------------------------------------------------------
__global__ __launch_bounds__(256)
void prep_kernel(const float* __restrict__ X, const float* __restrict__ S,
                 const float* __restrict__ Wg, const float* __restrict__ Wk,
                 const float* __restrict__ Wm1, const float* __restrict__ Wgt1,
                 const float* __restrict__ Wm2, const float* __restrict__ Wqkv,
                 const float* __restrict__ Wo, const float* __restrict__ Wu1,
                 const float* __restrict__ Wu2,
                 bf16_t* __restrict__ Xb, bf16_t* __restrict__ Sb,
                 bf16_t* __restrict__ W1t, bf16_t* __restrict__ W2t,
                 bf16_t* __restrict__ Wqkvt, bf16_t* __restrict__ Wot,
                 bf16_t* __restrict__ Wu1t, bf16_t* __restrict__ Wu2t,
                 float4* __restrict__ zbase)
{
  const int bid = blockIdx.x;
  const int t = threadIdx.x;
  if (bid < 8192) {                       // X
    const int i = bid * 256 + t;
    const float4 v = ((const float4*)X)[i];
    bf16x4v o; o[0]=(bf16_t)v.x; o[1]=(bf16_t)v.y; o[2]=(bf16_t)v.z; o[3]=(bf16_t)v.w;
    ((bf16x4v*)Xb)[i] = o;
  } else if (bid < 9216) {                // S
    const int i = (bid - 8192) * 256 + t;
    const float4 v = ((const float4*)S)[i];
    bf16x4v o; o[0]=(bf16_t)v.x; o[1]=(bf16_t)v.y; o[2]=(bf16_t)v.z; o[3]=(bf16_t)v.w;
    ((bf16x4v*)Sb)[i] = o;
  } else if (bid < 10112) {               // W1t: 896 rows x 256
    const int n = bid - 9216;
    const int k = t;
    float v;
    if (n < 512)      v = Wm1[k * 512 + n];
    else if (n < 768) v = Wgt1[k * 256 + (n - 512)];
    else if (n < 832) v = Wg[k * 64 + (n - 768)];
    else if (n < 840) v = Wk[k * 8 + (n - 832)];
    else              v = 0.f;
    W1t[n * 256 + k] = (bf16_t)v;
  } else if (bid < 10368) {               // W2t: 256 rows x 512
    const int n = bid - 10112;
    for (int k = t; k < 512; k += 256) W2t[n * 512 + k] = (bf16_t)Wm2[k * 256 + n];
  } else if (bid < 11136) {               // Wqkvt: 768 x 256
    const int n = bid - 10368;
    Wqkvt[n * 256 + t] = (bf16_t)Wqkv[t * 768 + n];
  } else if (bid < 11392) {               // Wot: 256 x 256
    const int n = bid - 11136;
    Wot[n * 256 + t] = (bf16_t)Wo[t * 256 + n];
  } else if (bid < 11904) {               // Wu1t: 512 x 512
    const int n = bid - 11392;
    for (int k = t; k < 512; k += 256) Wu1t[n * 512 + k] = (bf16_t)Wu1[k * 512 + n];
  } else if (bid < 12160) {               // Wu2t: 256 x 512
    const int n = bid - 11904;
    for (int k = t; k < 512; k += 256) Wu2t[n * 512 + k] = (bf16_t)Wu2[k * 256 + n];
  } else {                                // zero bitmap (2MB) + gatelin (128KB)
    zbase[(bid - 12160) * 256 + t] = make_float4(0.f, 0.f, 0.f, 0.f);
  }
}

// ---------------------------------------------------------------------------
// bf16 MFMA GEMM: C[M x N] = A[M x K] * Bt[N x K]^T, tile (MT*32) x 128, BK=32
// MFMA operands swapped: lane's 4 acc regs = 4 consecutive cols of one row.
// EPI 1 (G1R): by<4 -> gelu(+bm1) -> h1 (ldc=512)
//              by 4/5 -> gelu(+bgt1), dot with Wgt2 -> atomicAdd gatelin
//              by 6 -> argmax(Wg),argmax(Wk) -> bitmap atomicOr
// EPI 5: gelu(+bias) -> bf16
// ---------------------------------------------------------------------------
template<int MT, int EPI>
__global__ __launch_bounds__(256)
void gemm_kernel(const bf16_t* __restrict__ A, int lda,
                 const bf16_t* __restrict__ Bt, int K,
                 const float* __restrict__ bias, const float* __restrict__ bias2,
                 void* __restrict__ outp, int ldc,
                 const float* __restrict__ wgt2, float* __restrict__ gatelin,
                 u64* __restrict__ bitmap)
{
  constexpr int BM = MT * 32;
  constexpr int CA = BM * 4;             // 16B chunks per k-pass (A)
  const int m0 = blockIdx.x * BM;
  const int by = blockIdx.y;
  const int n0 = by * 128;
  const int t = threadIdx.x;
  const int w = t >> 6;
  const int lane = t & 63;
  const int wr = w >> 1, wc = w & 1;
  const int quad = lane >> 4, l15 = lane & 15;

  __shared__ bf16_t lA[BM * 32];
  __shared__ bf16_t lB[128 * 32];
  __shared__ float sWg[256];
  __shared__ int sKi[BM];

  if constexpr (EPI == 1) {
    if (by >= 4 && by < 6) sWg[t] = wgt2[t];
  }

  f32x4 acc[MT][4];
#pragma unroll
  for (int mt = 0; mt < MT; ++mt)
#pragma unroll
    for (int nt = 0; nt < 4; ++nt)
      acc[mt][nt] = (f32x4){0.f, 0.f, 0.f, 0.f};

  for (int k0 = 0; k0 < K; k0 += 32) {
    if constexpr (CA >= 256) {
#pragma unroll
      for (int i = 0; i < CA / 256; ++i) {
        const int c = i * 256 + t;
        async16(A + (size_t)(m0 + (c >> 2)) * lda + k0 + (c & 3) * 8,
                lA + (size_t)(i * 256 + (t & 192)) * 8);
      }
    } else {
      if (t < CA)
        async16(A + (size_t)(m0 + (t >> 2)) * lda + k0 + (t & 3) * 8,
                lA + (size_t)(t & 192) * 8);
    }
#pragma unroll
    for (int i = 0; i < 2; ++i) {
      const int c = i * 256 + t;
      async16(Bt + (size_t)(n0 + (c >> 2)) * K + k0 + (c & 3) * 8,
              lB + (size_t)(i * 256 + (t & 192)) * 8);
    }
    __syncthreads();
    bf16x8 af[MT], bfr[4];
    const int ko = quad * 8;
#pragma unroll
    for (int mt = 0; mt < MT; ++mt)
      af[mt] = *(const bf16x8*)&lA[(wr * MT * 16 + mt * 16 + l15) * 32 + ko];
#pragma unroll
    for (int nt = 0; nt < 4; ++nt)
      bfr[nt] = *(const bf16x8*)&lB[(wc * 64 + nt * 16 + l15) * 32 + ko];
#pragma unroll
    for (int mt = 0; mt < MT; ++mt)
#pragma unroll
      for (int nt = 0; nt < 4; ++nt)
        acc[mt][nt] = __builtin_amdgcn_mfma_f32_16x16x32_bf16(bfr[nt], af[mt], acc[mt][nt], 0, 0, 0);
    __syncthreads();
  }

  if constexpr (EPI == 1) {
    if (by < 4) {
      // msg: gelu(v + bm1) -> h1 bf16, ldc = 512
#pragma unroll
      for (int mt = 0; mt < MT; ++mt) {
        const int row = m0 + wr * MT * 16 + mt * 16 + l15;
#pragma unroll
        for (int nt = 0; nt < 4; ++nt) {
          const int colb = n0 + wc * 64 + nt * 16 + quad * 4;
          const float4 bb = *(const float4*)&bias[colb];
          bf16x4v o;
          o[0] = (bf16_t)gelu_f(acc[mt][nt][0] + bb.x);
          o[1] = (bf16_t)gelu_f(acc[mt][nt][1] + bb.y);
          o[2] = (bf16_t)gelu_f(acc[mt][nt][2] + bb.z);
          o[3] = (bf16_t)gelu_f(acc[mt][nt][3] + bb.w);
          *(bf16x4v*)&((bf16_t*)outp)[(size_t)row * 512 + colb] = o;
        }
      }
    } else if (by < 6) {
      // gate strips: partial dot of gelu(g1) with Wgt2 -> atomicAdd gatelin
#pragma unroll
      for (int mt = 0; mt < MT; ++mt) {
        const int row = m0 + wr * MT * 16 + mt * 16 + l15;
        float part = 0.f;
#pragma unroll
        for (int nt = 0; nt < 4; ++nt) {
          const int colb = n0 + wc * 64 + nt * 16 + quad * 4;
          const int c = colb - 512;
          const float4 bb = *(const float4*)&bias2[c];
          part = fmaf(gelu_f(acc[mt][nt][0] + bb.x), sWg[c + 0], part);
          part = fmaf(gelu_f(acc[mt][nt][1] + bb.y), sWg[c + 1], part);
          part = fmaf(gelu_f(acc[mt][nt][2] + bb.z), sWg[c + 2], part);
          part = fmaf(gelu_f(acc[mt][nt][3] + bb.w), sWg[c + 3], part);
        }
        part += __shfl_xor(part, 16, 64);
        part += __shfl_xor(part, 32, 64);
        if (lane < 16) atomicAdd(&gatelin[row], part);
      }
    } else {
      // logit strip: argmax(g)*8 + argmax(k) -> bitmap
      int bi[MT];
#pragma unroll
      for (int mt = 0; mt < MT; ++mt) {
        if (wc == 0) {
          float mv = -1e30f; int mi = 0;
#pragma unroll
          for (int nt = 0; nt < 4; ++nt)
#pragma unroll
            for (int j = 0; j < 4; ++j) {
              const int gc = nt * 16 + quad * 4 + j;
              const float v = acc[mt][nt][j];
              if (v > mv || (v == mv && gc < mi)) { mv = v; mi = gc; }
            }
#pragma unroll
          for (int off = 16; off <= 32; off <<= 1) {
            const float ov = __shfl_xor(mv, off, 64);
            const int oi = __shfl_xor(mi, off, 64);
            if (ov > mv || (ov == mv && oi < mi)) { mv = ov; mi = oi; }
          }
          bi[mt] = mi;
        } else {
          float mv = -1e30f; int mi = 0;
          if (quad < 2) {
#pragma unroll
            for (int j = 0; j < 4; ++j) {
              const int kc = quad * 4 + j;
              const float v = acc[mt][0][j];
              if (v > mv || (v == mv && kc < mi)) { mv = v; mi = kc; }
            }
          }
#pragma unroll
          for (int off = 16; off <= 32; off <<= 1) {
            const float ov = __shfl_xor(mv, off, 64);
            const int oi = __shfl_xor(mi, off, 64);
            if (ov > mv || (ov == mv && oi < mi)) { mv = ov; mi = oi; }
          }
          if (lane < 16) sKi[wr * MT * 16 + mt * 16 + l15] = mi;
        }
      }
      __syncthreads();
      if (wc == 0 && lane < 16) {
#pragma unroll
        for (int mt = 0; mt < MT; ++mt) {
          const int rl = wr * MT * 16 + mt * 16 + l15;
          const int row = m0 + rl;
          const int idx = bi[mt] * 8 + sKi[rl];
          const int b = row >> 12, tok = row & 4095;
          atomicOr(&bitmap[(size_t)(b * 512 + idx) * 64 + (tok >> 6)],
                   1ull << (tok & 63));
        }
      }
    }
  } else {  // EPI 5: gelu(+bias) -> bf16
#pragma unroll
    for (int mt = 0; mt < MT; ++mt) {
      const int row = m0 + wr * MT * 16 + mt * 16 + l15;
#pragma unroll
      for (int nt = 0; nt < 4; ++nt) {
        const int colb = n0 + wc * 64 + nt * 16 + quad * 4;
        const float4 bb = *(const float4*)&bias[colb];
        bf16x4v o;
        o[0]=(bf16_t)gelu_f(acc[mt][nt][0]+bb.x); o[1]=(bf16_t)gelu_f(acc[mt][nt][1]+bb.y);
        o[2]=(bf16_t)gelu_f(acc[mt][nt][2]+bb.z); o[3]=(bf16_t)gelu_f(acc[mt][nt][3]+bb.w);
        *(bf16x4v*)&((bf16_t*)outp)[(size_t)row * ldc + colb] = o;
      }
    }
  }
}

// ---------------------------------------------------------------------------
// pair: blocks [0,256) = G2' (incoming = H@Wm2 + sumg*bm2, f32)
//       blocks [256,1024) = qkv (Sb@Wqkvt + bqkv, bf16)
// ---------------------------------------------------------------------------
__global__ __launch_bounds__(256)
void gemm_pair_kernel(const bf16_t* __restrict__ H, const bf16_t* __restrict__ W2t,
                      const float* __restrict__ bm2, const float* __restrict__ sumg,
                      float* __restrict__ incom,
                      const bf16_t* __restrict__ Sb, const bf16_t* __restrict__ Wqkvt,
                      const float* __restrict__ bqkv, bf16_t* __restrict__ qkvb)
{
  int id = blockIdx.x;
  const bool first = id < 256;
  if (!first) id -= 256;
  const bf16_t* A  = first ? H : Sb;
  const bf16_t* Bt = first ? W2t : Wqkvt;
  const float* bias = first ? bm2 : bqkv;
  const int lda = first ? 512 : 256;
  const int K   = first ? 512 : 256;
  const int ldc = first ? 256 : 768;
  const int m0 = (id & 127) * 32;
  const int n0 = (id >> 7) * 128;
  const int t = threadIdx.x;
  const int w = t >> 6;
  const int lane = t & 63;
  const int wr = w >> 1, wc = w & 1;
  const int quad = lane >> 4, l15 = lane & 15;

  __shared__ bf16_t lA[32 * 32];
  __shared__ bf16_t lB[128 * 32];

  f32x4 acc[4];
#pragma unroll
  for (int nt = 0; nt < 4; ++nt) acc[nt] = (f32x4){0.f, 0.f, 0.f, 0.f};

  for (int k0 = 0; k0 < K; k0 += 32) {
    if (t < 128)
      async16(A + (size_t)(m0 + (t >> 2)) * lda + k0 + (t & 3) * 8,
              lA + (size_t)(t & 192) * 8);
#pragma unroll
    for (int i = 0; i < 2; ++i) {
      const int c = i * 256 + t;
      async16(Bt + (size_t)(n0 + (c >> 2)) * K + k0 + (c & 3) * 8,
              lB + (size_t)(i * 256 + (t & 192)) * 8);
    }
    __syncthreads();
    bf16x8 af, bfr[4];
    const int ko = quad * 8;
    af = *(const bf16x8*)&lA[(wr * 16 + l15) * 32 + ko];
#pragma unroll
    for (int nt = 0; nt < 4; ++nt)
      bfr[nt] = *(const bf16x8*)&lB[(wc * 64 + nt * 16 + l15) * 32 + ko];
#pragma unroll
    for (int nt = 0; nt < 4; ++nt)
      acc[nt] = __builtin_amdgcn_mfma_f32_16x16x32_bf16(bfr[nt], af, acc[nt], 0, 0, 0);
    __syncthreads();
  }

  const int row = m0 + wr * 16 + l15;
  if (first) {
    const float gt = sumg[row];
#pragma unroll
    for (int nt = 0; nt < 4; ++nt) {
      const int colb = n0 + wc * 64 + nt * 16 + quad * 4;
      const float4 bb = *(const float4*)&bias[colb];
      *(float4*)&incom[(size_t)row * ldc + colb] =
          make_float4(fmaf(gt, bb.x, acc[nt][0]), fmaf(gt, bb.y, acc[nt][1]),
                      fmaf(gt, bb.z, acc[nt][2]), fmaf(gt, bb.w, acc[nt][3]));
    }
  } else {
#pragma unroll
    for (int nt = 0; nt < 4; ++nt) {
      const int colb = n0 + wc * 64 + nt * 16 + quad * 4;
      const float4 bb = *(const float4*)&bias[colb];
      bf16x4v o; o[0]=(bf16_t)(acc[nt][0]+bb.x); o[1]=(bf16_t)(acc[nt][1]+bb.y);
      o[2]=(bf16_t)(acc[nt][2]+bb.z); o[3]=(bf16_t)(acc[nt][3]+bb.w);
      *(bf16x4v*)&qkvb[(size_t)row * ldc + colb] = o;
    }
  }
}

// ---------------------------------------------------------------------------
// gather: block per (b,slot); bitmap-driven; H = sum gate*h1 rows; sumg
// ---------------------------------------------------------------------------
__global__ __launch_bounds__(256)
void gather_kernel(const bf16_t* __restrict__ h1, const float* __restrict__ gatelin,
                   const float* __restrict__ bgt2, const u64* __restrict__ bitmap,
                   bf16_t* __restrict__ H, float* __restrict__ sumg)
{
  const int bs = blockIdx.x;
  const int b = bs >> 9;
  const int t = threadIdx.x;
  __shared__ u64 sw[64];
  if (t < 64) sw[t] = bitmap[(size_t)bs * 64 + t];
  __syncthreads();
  const float bg = bgt2[0];
  float a0 = 0.f, a1 = 0.f, sg = 0.f;
  for (int wd = 0; wd < 64; ++wd) {
    u64 word = sw[wd];
    while (word) {
      const int bit = __builtin_ctzll(word);
      word &= word - 1;
      const int l = (b << 12) + (wd << 6) + bit;
      const float g = 1.0f / (1.0f + __expf(-(gatelin[l] + bg)));
      const bf16x2v hv = *(const bf16x2v*)&h1[(size_t)l * 512 + t * 2];
      a0 = fmaf(g, (float)hv[0], a0);
      a1 = fmaf(g, (float)hv[1], a1);
      sg += g;
    }
  }
  bf16x2v o; o[0] = (bf16_t)a0; o[1] = (bf16_t)a1;
  *(bf16x2v*)&H[(size_t)bs * 512 + t * 2] = o;
  if (t == 0) sumg[bs] = sg;
}

// ---------------------------------------------------------------------------
// fused slot attention: block = (b, h, 32-query chunk)
// ---------------------------------------------------------------------------
__global__ __launch_bounds__(256)
void attn_kernel(const bf16_t* __restrict__ qkv, bf16_t* __restrict__ obuf)
{
  const int bid = blockIdx.x;
  const int qc = bid & 15;
  const int h = (bid >> 4) & 7;
  const int b = bid >> 7;
  const int t = threadIdx.x;
  const int w = t >> 6, lane = t & 63;
  const int quad = lane >> 4, l15 = lane & 15;

  __shared__ bf16_t sP[32 * 520];
  __shared__ bf16_t sVt[32 * 264];
  __shared__ float sL[32];

  bf16x8 qf[2];
#pragma unroll
  for (int mt = 0; mt < 2; ++mt) {
    const int row = b * 512 + qc * 32 + mt * 16 + l15;
    qf[mt] = *(const bf16x8*)&qkv[(size_t)row * 768 + h * 32 + quad * 8];
  }
  const float scale = 0.17677669529663687f;  // 1/sqrt(32)
  for (int kt = w; kt < 32; kt += 4) {
    const int key = b * 512 + kt * 16 + l15;
    const bf16x8 kf = *(const bf16x8*)&qkv[(size_t)key * 768 + 256 + h * 32 + quad * 8];
#pragma unroll
    for (int mt = 0; mt < 2; ++mt) {
      f32x4 c = (f32x4){0.f, 0.f, 0.f, 0.f};
      c = __builtin_amdgcn_mfma_f32_16x16x32_bf16(qf[mt], kf, c, 0, 0, 0);
#pragma unroll
      for (int r = 0; r < 4; ++r)
        sP[(mt * 16 + quad * 4 + r) * 520 + kt * 16 + l15] = (bf16_t)(c[r] * scale);
    }
  }
  __syncthreads();

#pragma unroll
  for (int ri = 0; ri < 8; ++ri) {
    const int row = w * 8 + ri;
    const bf16x8 sv = *(const bf16x8*)&sP[row * 520 + lane * 8];
    float sval[8];
    float mx = -1e30f;
#pragma unroll
    for (int j = 0; j < 8; ++j) { sval[j] = (float)sv[j]; mx = fmaxf(mx, sval[j]); }
#pragma unroll
    for (int off = 32; off; off >>= 1) mx = fmaxf(mx, __shfl_xor(mx, off, 64));
    float sum = 0.f;
    bf16x8 pv;
#pragma unroll
    for (int j = 0; j < 8; ++j) { const float e = __expf(sval[j] - mx); sum += e; pv[j] = (bf16_t)e; }
#pragma unroll
    for (int off = 32; off; off >>= 1) sum += __shfl_xor(sum, off, 64);
    *(bf16x8*)&sP[row * 520 + lane * 8] = pv;
    if (lane == 0) sL[row] = sum;
  }
  __syncthreads();

  const int omt = w >> 1, ont = w & 1;
  f32x4 oacc = (f32x4){0.f, 0.f, 0.f, 0.f};
  for (int half = 0; half < 2; ++half) {
    if (half) __syncthreads();
#pragma unroll
    for (int i = 0; i < 32; ++i) {
      const int el = i * 256 + t;
      const int dh = el & 31, key = el >> 5;
      sVt[dh * 264 + key] = qkv[(size_t)(b * 512 + half * 256 + key) * 768 + 512 + h * 32 + dh];
    }
    __syncthreads();
#pragma unroll
    for (int kt = 0; kt < 8; ++kt) {
      const bf16x8 af = *(const bf16x8*)&sP[(omt * 16 + l15) * 520 + half * 256 + kt * 32 + quad * 8];
      const bf16x8 vf = *(const bf16x8*)&sVt[(ont * 16 + l15) * 264 + kt * 32 + quad * 8];
      oacc = __builtin_amdgcn_mfma_f32_16x16x32_bf16(af, vf, oacc, 0, 0, 0);
    }
  }
#pragma unroll
  for (int r = 0; r < 4; ++r) {
    const int row = omt * 16 + quad * 4 + r;
    const float val = oacc[r] / sL[row];
    obuf[(size_t)(b * 512 + qc * 32 + row) * 256 + h * 32 + ont * 16 + l15] = (bf16_t)val;
  }
}

// ---------------------------------------------------------------------------
// wo_ln1: o2 = obuf@Wot + bo ; S1 = LN(S + o2) ; S1f f32 ; A4 = [S1|incom] bf16
// block = 16 rows x 256 cols (full width), 4 waves each own 64 cols
// ---------------------------------------------------------------------------
__global__ __launch_bounds__(256)
void wo_ln1_kernel(const bf16_t* __restrict__ obuf, const bf16_t* __restrict__ Wot,
                   const float* __restrict__ bo, const float* __restrict__ S,
                   const float* __restrict__ incom, const float* __restrict__ g,
                   const float* __restrict__ bb, float* __restrict__ S1f,
                   bf16_t* __restrict__ A4)
{
  const int m0 = blockIdx.x * 16;
  const int t = threadIdx.x;
  const int w = t >> 6, lane = t & 63;
  const int quad = lane >> 4, l15 = lane & 15;

  __shared__ bf16_t lA[16 * 32];
  __shared__ bf16_t lB[256 * 32];
  __shared__ float sSum[4][16];
  __shared__ float sSq[4][16];

  f32x4 acc[4];
#pragma unroll
  for (int nt = 0; nt < 4; ++nt) acc[nt] = (f32x4){0.f, 0.f, 0.f, 0.f};

  for (int k0 = 0; k0 < 256; k0 += 32) {
    if (t < 64)
      async16(obuf + (size_t)(m0 + (t >> 2)) * 256 + k0 + (t & 3) * 8, lA);
#pragma unroll
    for (int i = 0; i < 4; ++i) {
      const int c = i * 256 + t;
      async16(Wot + (size_t)(c >> 2) * 256 + k0 + (c & 3) * 8,
              lB + (size_t)(i * 256 + (t & 192)) * 8);
    }
    __syncthreads();
    const int ko = quad * 8;
    const bf16x8 af = *(const bf16x8*)&lA[l15 * 32 + ko];
#pragma unroll
    for (int nt = 0; nt < 4; ++nt) {
      const bf16x8 bfr = *(const bf16x8*)&lB[(w * 64 + nt * 16 + l15) * 32 + ko];
      acc[nt] = __builtin_amdgcn_mfma_f32_16x16x32_bf16(bfr, af, acc[nt], 0, 0, 0);
    }
    __syncthreads();
  }

  const int row = m0 + l15;
  float sum = 0.f, sq = 0.f;
#pragma unroll
  for (int nt = 0; nt < 4; ++nt) {
    const int colb = w * 64 + nt * 16 + quad * 4;
    const float4 bv = *(const float4*)&bo[colb];
    const float4 sv = *(const float4*)&S[(size_t)row * 256 + colb];
    float x0 = acc[nt][0] + bv.x + sv.x, x1 = acc[nt][1] + bv.y + sv.y;
    float x2 = acc[nt][2] + bv.z + sv.z, x3 = acc[nt][3] + bv.w + sv.w;
    acc[nt][0] = x0; acc[nt][1] = x1; acc[nt][2] = x2; acc[nt][3] = x3;
    sum += x0 + x1 + x2 + x3;
    sq += x0*x0 + x1*x1 + x2*x2 + x3*x3;
  }
  sum += __shfl_xor(sum, 16, 64); sum += __shfl_xor(sum, 32, 64);
  sq  += __shfl_xor(sq, 16, 64);  sq  += __shfl_xor(sq, 32, 64);
  if (lane < 16) { sSum[w][l15] = sum; sSq[w][l15] = sq; }
  __syncthreads();
  const float tot = sSum[0][l15] + sSum[1][l15] + sSum[2][l15] + sSum[3][l15];
  const float tq  = sSq[0][l15] + sSq[1][l15] + sSq[2][l15] + sSq[3][l15];
  const float mean = tot * 0.00390625f;
  const float var = tq * 0.00390625f - mean * mean;
  const float rstd = rsqrtf(var + LN_EPS);
#pragma unroll
  for (int nt = 0; nt < 4; ++nt) {
    const int colb = w * 64 + nt * 16 + quad * 4;
    const float4 gg = *(const float4*)&g[colb];
    const float4 bv = *(const float4*)&bb[colb];
    const float y0 = (acc[nt][0]-mean)*rstd*gg.x + bv.x;
    const float y1 = (acc[nt][1]-mean)*rstd*gg.y + bv.y;
    const float y2 = (acc[nt][2]-mean)*rstd*gg.z + bv.z;
    const float y3 = (acc[nt][3]-mean)*rstd*gg.w + bv.w;
    *(float4*)&S1f[(size_t)row * 256 + colb] = make_float4(y0, y1, y2, y3);
    bf16x4v yb; yb[0]=(bf16_t)y0; yb[1]=(bf16_t)y1; yb[2]=(bf16_t)y2; yb[3]=(bf16_t)y3;
    *(bf16x4v*)&A4[(size_t)row * 512 + colb] = yb;
    const float4 ic = *(const float4*)&incom[(size_t)row * 256 + colb];
    bf16x4v ib; ib[0]=(bf16_t)ic.x; ib[1]=(bf16_t)ic.y; ib[2]=(bf16_t)ic.z; ib[3]=(bf16_t)ic.w;
    *(bf16x4v*)&A4[(size_t)row * 512 + 256 + colb] = ib;
  }
}

// ---------------------------------------------------------------------------
// wu2_ln2: S2 = U@Wu2t + bu2 + S1f ; out = LN(S2)  (final output, f32)
// ---------------------------------------------------------------------------
__global__ __launch_bounds__(256)
void wu2_ln2_kernel(const bf16_t* __restrict__ U, const bf16_t* __restrict__ Wu2t,
                    const float* __restrict__ bu2, const float* __restrict__ S1f,
                    const float* __restrict__ g, const float* __restrict__ bb,
                    float* __restrict__ out)
{
  const int m0 = blockIdx.x * 16;
  const int t = threadIdx.x;
  const int w = t >> 6, lane = t & 63;
  const int quad = lane >> 4, l15 = lane & 15;

  __shared__ bf16_t lA[16 * 32];
  __shared__ bf16_t lB[256 * 32];
  __shared__ float sSum[4][16];
  __shared__ float sSq[4][16];

  f32x4 acc[4];
#pragma unroll
  for (int nt = 0; nt < 4; ++nt) acc[nt] = (f32x4){0.f, 0.f, 0.f, 0.f};

  for (int k0 = 0; k0 < 512; k0 += 32) {
    if (t < 64)
      async16(U + (size_t)(m0 + (t >> 2)) * 512 + k0 + (t & 3) * 8, lA);
#pragma unroll
    for (int i = 0; i < 4; ++i) {
      const int c = i * 256 + t;
      async16(Wu2t + (size_t)(c >> 2) * 512 + k0 + (c & 3) * 8,
              lB + (size_t)(i * 256 + (t & 192)) * 8);
    }
    __syncthreads();
    const int ko = quad * 8;
    const bf16x8 af = *(const bf16x8*)&lA[l15 * 32 + ko];
#pragma unroll
    for (int nt = 0; nt < 4; ++nt) {
      const bf16x8 bfr = *(const bf16x8*)&lB[(w * 64 + nt * 16 + l15) * 32 + ko];
      acc[nt] = __builtin_amdgcn_mfma_f32_16x16x32_bf16(bfr, af, acc[nt], 0, 0, 0);
    }
    __syncthreads();
  }

  const int row = m0 + l15;
  float sum = 0.f, sq = 0.f;
#pragma unroll
  for (int nt = 0; nt < 4; ++nt) {
    const int colb = w * 64 + nt * 16 + quad * 4;
    const float4 bv = *(const float4*)&bu2[colb];
    const float4 sv = *(const float4*)&S1f[(size_t)row * 256 + colb];
    float x0 = acc[nt][0] + bv.x + sv.x, x1 = acc[nt][1] + bv.y + sv.y;
    float x2 = acc[nt][2] + bv.z + sv.z, x3 = acc[nt][3] + bv.w + sv.w;
    acc[nt][0] = x0; acc[nt][1] = x1; acc[nt][2] = x2; acc[nt][3] = x3;
    sum += x0 + x1 + x2 + x3;
    sq += x0*x0 + x1*x1 + x2*x2 + x3*x3;
  }
  sum += __shfl_xor(sum, 16, 64); sum += __shfl_xor(sum, 32, 64);
  sq  += __shfl_xor(sq, 16, 64);  sq  += __shfl_xor(sq, 32, 64);
  if (lane < 16) { sSum[w][l15] = sum; sSq[w][l15] = sq; }
  __syncthreads();
  const float tot = sSum[0][l15] + sSum[1][l15] + sSum[2][l15] + sSum[3][l15];
  const float tq  = sSq[0][l15] + sSq[1][l15] + sSq[2][l15] + sSq[3][l15];
  const float mean = tot * 0.00390625f;
  const float var = tq * 0.00390625f - mean * mean;
  const float rstd = rsqrtf(var + LN_EPS);
#pragma unroll
  for (int nt = 0; nt < 4; ++nt) {
    const int colb = w * 64 + nt * 16 + quad * 4;
    const float4 gg = *(const float4*)&g[colb];
    const float4 bv = *(const float4*)&bb[colb];
    *(float4*)&out[(size_t)row * 256 + colb] = make_float4(
        (acc[nt][0]-mean)*rstd*gg.x + bv.x, (acc[nt][1]-mean)*rstd*gg.y + bv.y,
        (acc[nt][2]-mean)*rstd*gg.z + bv.z, (acc[nt][3]-mean)*rstd*gg.w + bv.w);
  }
}

// ---------------------------------------------------------------------------
extern "C" void kernel_launch(void* const* d_in, const int* in_sizes, int n_in,
                              void* d_out, int out_size, void* d_ws, size_t ws_size,
                              hipStream_t stream)
{
  (void)in_sizes; (void)n_in; (void)out_size; (void)ws_size;
  const float* X    = (const float*)d_in[0];
  const float* S    = (const float*)d_in[1];
  const float* Wg   = (const float*)d_in[2];
  const float* Wk   = (const float*)d_in[3];
  const float* Wm1  = (const float*)d_in[4];
  const float* bm1  = (const float*)d_in[5];
  const float* Wm2  = (const float*)d_in[6];
  const float* bm2  = (const float*)d_in[7];
  const float* Wgt1 = (const float*)d_in[8];
  const float* bgt1 = (const float*)d_in[9];
  const float* Wgt2 = (const float*)d_in[10];
  const float* bgt2 = (const float*)d_in[11];
  const float* Wqkv = (const float*)d_in[12];
  const float* bqkv = (const float*)d_in[13];
  const float* Wo   = (const float*)d_in[14];
  const float* bo   = (const float*)d_in[15];
  const float* alng = (const float*)d_in[16];
  const float* alnb = (const float*)d_in[17];
  const float* Wu1  = (const float*)d_in[18];
  const float* bu1  = (const float*)d_in[19];
  const float* Wu2  = (const float*)d_in[20];
  const float* bu2  = (const float*)d_in[21];
  const float* lng  = (const float*)d_in[22];
  const float* lnb  = (const float*)d_in[23];

  char* p = (char*)d_ws;
  auto carve = [&](size_t bytes) { char* r = p; p += bytes; return r; };
  bf16_t* Xb    = (bf16_t*)carve(16777216);   // 32768 x 256
  bf16_t* Sb    = (bf16_t*)carve(2097152);    // 4096 x 256
  bf16_t* W1t   = (bf16_t*)carve(458752);     // 896 x 256
  bf16_t* W2t   = (bf16_t*)carve(262144);     // 256 x 512
  bf16_t* Wqkvt = (bf16_t*)carve(393216);     // 768 x 256
  bf16_t* Wot   = (bf16_t*)carve(131072);     // 256 x 256
  bf16_t* Wu1t  = (bf16_t*)carve(524288);     // 512 x 512
  bf16_t* Wu2t  = (bf16_t*)carve(262144);     // 256 x 512
  bf16_t* h1    = (bf16_t*)carve(33554432);   // 32768 x 512 (msg only)
  u64*    bitmap  = (u64*)carve(2097152);     // 4096 slots x 64 words (zeroed by prep)
  float*  gatelin = (float*)carve(131072);    // 32768 (zeroed by prep, adjacent)
  float*  incom = (float*)carve(4194304);     // 4096 x 256 f32
  bf16_t* qkvb  = (bf16_t*)carve(6291456);    // 4096 x 768
  bf16_t* obuf  = (bf16_t*)carve(2097152);    // 4096 x 256
  float*  S1f   = (float*)carve(4194304);
  bf16_t* A4    = (bf16_t*)carve(4194304);    // 4096 x 512
  bf16_t* U     = (bf16_t*)carve(4194304);    // 4096 x 512 (aliased by H)
  float*  sumg  = (float*)carve(16384);
  bf16_t* H = U;  // disjoint lifetime: H dead before U written

  // 1. prep (+ zero bitmap & gatelin: 2228224 B = 544 blocks x 4 KB)
  prep_kernel<<<12704, 256, 0, stream>>>(X, S, Wg, Wk, Wm1, Wgt1, Wm2, Wqkv, Wo, Wu1, Wu2,
                                         Xb, Sb, W1t, W2t, Wqkvt, Wot, Wu1t, Wu2t,
                                         (float4*)bitmap);
  // 2. G1 + fused routing (BM=64 for occupancy)
  gemm_kernel<2,1><<<dim3(512,7), 256, 0, stream>>>(Xb, 256, W1t, 256, bm1, bgt1, h1, 512,
                                                    Wgt2, gatelin, bitmap);
  // 3. bitmap-driven aggregate
  gather_kernel<<<4096, 256, 0, stream>>>(h1, gatelin, bgt2, bitmap, H, sumg);
  // 4. G2' (incoming) + qkv in one dispatch
  gemm_pair_kernel<<<1024, 256, 0, stream>>>(H, W2t, bm2, sumg, incom,
                                             Sb, Wqkvt, bqkv, qkvb);
  // 5. attention
  attn_kernel<<<1024, 256, 0, stream>>>(qkvb, obuf);
  // 6. Wo GEMM + LN1 + pack (fused)
  wo_ln1_kernel<<<256, 256, 0, stream>>>(obuf, Wot, bo, S, incom, alng, alnb, S1f, A4);
  // 7. update MLP hidden
  gemm_kernel<1,5><<<dim3(128,4), 256, 0, stream>>>(A4, 512, Wu1t, 512, bu1, nullptr, U, 512,
                                                    nullptr, nullptr, nullptr);
  // 8. update MLP out + residual + LN2 (fused) -> d_out
  wu2_ln2_kernel<<<256, 256, 0, stream>>>(U, Wu2t, bu2, S1f, lng, lnb, (float*)d_out);
}